// Round 4
// baseline (1012.563 us; speedup 1.0000x reference)
//
#include <hip/hip_runtime.h>

#define NN 131072        // nodes
#define EE 2097152       // edges
#define SS 32            // channels
#define HH 16            // hidden
#define BB 4096          // graphs
#define EPS 1e-5f

#define BKT 512          // buckets (dst >> 8)
#define BNODES 256       // nodes per bucket
#define CAP 4864         // bucket capacity (avg 4096, +12 sigma)

// ---------------- coarse bucket partition of edges by dst>>8 ----------------
// Per-block tile = 8192 edges. LDS histogram -> reserve global base per bucket ->
// rank+write. Per tile each bucket receives ~16 CONTIGUOUS slots written from one
// CU => lines fill within one XCD's L2 => ~no write amplification (R3 lesson:
// random 4B scatter wrote 135 MB HBM for an 8 MB payload).
__global__ __launch_bounds__(256) void k_bsort(const int* __restrict__ ei, int* __restrict__ gcount,
                                               int* __restrict__ words) {
    __shared__ int hist[BKT];
    __shared__ int base[BKT];
    int t = threadIdx.x;
    for (int i = t; i < BKT; i += 256) hist[i] = 0;
    __syncthreads();
    int e0 = blockIdx.x * 8192;
    for (int it = 0; it < 32; ++it) {
        int dst = ei[EE + e0 + it * 256 + t];
        atomicAdd(&hist[dst >> 8], 1);
    }
    __syncthreads();
    for (int i = t; i < BKT; i += 256) {
        base[i] = atomicAdd(&gcount[i], hist[i]);
        hist[i] = 0;                    // reuse as intra-tile cursor
    }
    __syncthreads();
    for (int it = 0; it < 32; ++it) {
        int e = e0 + it * 256 + t;
        int src = ei[e];
        int dst = ei[EE + e];
        int b = dst >> 8;
        int r = atomicAdd(&hist[b], 1);
        words[(size_t)b * CAP + base[b] + r] = src | ((dst & 255) << 17);
    }
}

// ---------------- per-node pre-transform (u = x@(Wt-Wb)+b1, v = x@Wb) ----------------
__global__ __launch_bounds__(256) void k_pre1(const float* __restrict__ x, const float* __restrict__ W1,
                                              const float* __restrict__ b1, float* __restrict__ u,
                                              float* __restrict__ v) {
    int t = blockIdx.x * 256 + threadIdx.x;     // N*16 threads
    int n = t >> 4, c = t & 15;
    float x0 = x[n * 2], x1 = x[n * 2 + 1];
    float w0 = W1[c], w1 = W1[16 + c], w2 = W1[32 + c], w3 = W1[48 + c];
    u[t] = b1[c] + x0 * (w0 - w2) + x1 * (w1 - w3);
    v[t] = x0 * w2 + x1 * w3;
}

// layers 2/3: F=32 input features
__global__ __launch_bounds__(256) void k_pre32(const float* __restrict__ h, const float* __restrict__ W1,
                                               const float* __restrict__ b1, float* __restrict__ u,
                                               float* __restrict__ v) {
    __shared__ float sh[16][33];
    __shared__ float wd[32][16];
    __shared__ float wv[32][16];
    int t = threadIdx.x;
    for (int i = t; i < 512; i += 256) {
        int f = i >> 4, c = i & 15;
        float wt = W1[i];            // rows 0..31 (x_i part)
        float wb = W1[512 + i];      // rows 32..63 (x_j - x_i part)
        wd[f][c] = wt - wb;
        wv[f][c] = wb;
    }
    int nb = blockIdx.x * 16;
    for (int i = t; i < 512; i += 256) sh[i >> 5][i & 31] = h[nb * 32 + i];
    __syncthreads();
    int c = t & 15, nl = t >> 4;
    float uu = b1[c], vv = 0.f;
#pragma unroll
    for (int f = 0; f < 32; ++f) {
        float hv = sh[nl][f];
        uu += hv * wd[f][c];
        vv += hv * wv[f][c];
    }
    int n = nb + nl;
    u[n * 16 + c] = uu;
    v[n * 16 + c] = vv;
}

// ---------------- bucketed gather: LDS-atomic reduce + @W2, one block per bucket ----------------
__global__ __launch_bounds__(512) void k_bgather(const float* __restrict__ u, const float* __restrict__ v,
                                                 const int* __restrict__ words, const int* __restrict__ gcount,
                                                 const float* __restrict__ W2, const float* __restrict__ b2,
                                                 float* __restrict__ y) {
    __shared__ float uL[BNODES * 17];       // stride 17: conflict-free (17 coprime 32)
    __shared__ float agg[BNODES * 17];
    __shared__ int   cntL[BNODES];
    __shared__ float sW2[16 * 32];
    int t = threadIdx.x;
    int b = blockIdx.x;
    for (int i = t; i < 512; i += 512) sW2[i] = W2[i];
    for (int i = t; i < BNODES * 16; i += 512) {
        int nl = i >> 4, c = i & 15;
        uL[nl * 17 + c] = u[(size_t)b * (BNODES * 16) + i];     // coalesced read
        agg[nl * 17 + c] = 0.f;
    }
    for (int i = t; i < BNODES; i += 512) cntL[i] = 0;
    __syncthreads();

    int cnt = gcount[b];
    const int* wp = words + (size_t)b * CAP;
    int p = t;
    int w = (p < cnt) ? wp[p] : 0;
    while (p < cnt) {
        int pn = p + 512;
        int wn = (pn < cnt) ? wp[pn] : 0;    // prefetch next edge word
        int src = w & 0x1FFFF;
        int dl = w >> 17;
        const float4* vp = (const float4*)(v + (size_t)src * 16);
        float4 v0 = vp[0], v1 = vp[1], v2 = vp[2], v3 = vp[3];
        atomicAdd(&cntL[dl], 1);
        float* ub = &uL[dl * 17];
        float* ab = &agg[dl * 17];
        atomicAdd(&ab[0],  fmaxf(ub[0]  + v0.x, 0.f));
        atomicAdd(&ab[1],  fmaxf(ub[1]  + v0.y, 0.f));
        atomicAdd(&ab[2],  fmaxf(ub[2]  + v0.z, 0.f));
        atomicAdd(&ab[3],  fmaxf(ub[3]  + v0.w, 0.f));
        atomicAdd(&ab[4],  fmaxf(ub[4]  + v1.x, 0.f));
        atomicAdd(&ab[5],  fmaxf(ub[5]  + v1.y, 0.f));
        atomicAdd(&ab[6],  fmaxf(ub[6]  + v1.z, 0.f));
        atomicAdd(&ab[7],  fmaxf(ub[7]  + v1.w, 0.f));
        atomicAdd(&ab[8],  fmaxf(ub[8]  + v2.x, 0.f));
        atomicAdd(&ab[9],  fmaxf(ub[9]  + v2.y, 0.f));
        atomicAdd(&ab[10], fmaxf(ub[10] + v2.z, 0.f));
        atomicAdd(&ab[11], fmaxf(ub[11] + v2.w, 0.f));
        atomicAdd(&ab[12], fmaxf(ub[12] + v3.x, 0.f));
        atomicAdd(&ab[13], fmaxf(ub[13] + v3.y, 0.f));
        atomicAdd(&ab[14], fmaxf(ub[14] + v3.z, 0.f));
        atomicAdd(&ab[15], fmaxf(ub[15] + v3.w, 0.f));
        p = pn;
        w = wn;
    }
    __syncthreads();

    // epilogue: 2 threads per node, 16 output channels each
    int nl = t >> 1;
    int half = (t & 1) * 16;
    float cw = (float)cntL[nl];
    float o[16];
#pragma unroll
    for (int c = 0; c < 16; ++c) o[c] = b2[half + c] * cw;
#pragma unroll
    for (int k = 0; k < 16; ++k) {
        float a = agg[nl * 17 + k];          // pair shares address -> broadcast; 32 nl -> 32 banks
#pragma unroll
        for (int c = 0; c < 16; ++c) o[c] += a * sW2[k * 32 + half + c];
    }
    float* yp = y + (size_t)b * (BNODES * 32) + nl * 32 + half;
#pragma unroll
    for (int c = 0; c < 16; c += 4) *(float4*)(yp + c) = make_float4(o[c], o[c + 1], o[c + 2], o[c + 3]);
}

// ---------------- BN stats straight from y: 256 blocks x 512 rows ----------------
__global__ __launch_bounds__(256) void k_bnstat2(const float* __restrict__ y, float* __restrict__ bns) {
    __shared__ float ssm[8][33];
    __shared__ float ssq[8][33];
    int t = threadIdx.x;
    int c = t & 31, g = t >> 5;             // 8 row-groups
    size_t r0 = (size_t)blockIdx.x * 512;
    float sm = 0.f, sq = 0.f;
    for (int i = 0; i < 64; ++i) {
        float val = y[(r0 + g + (size_t)i * 8) * 32 + c];
        sm += val;
        sq += val * val;
    }
    ssm[g][c] = sm;
    ssq[g][c] = sq;
    __syncthreads();
    if (t < 32) {
        float a = 0.f, bq = 0.f;
#pragma unroll
        for (int gg = 0; gg < 8; ++gg) { a += ssm[gg][t]; bq += ssq[gg][t]; }
        atomicAdd(&bns[t], a);
        atomicAdd(&bns[32 + t], bq);
    }
}

// ---------------- BN (training-mode batch stats) + ReLU ----------------
__global__ __launch_bounds__(256) void k_bnrelu(const float* __restrict__ y, const float* __restrict__ bns,
                                                const float* __restrict__ g, const float* __restrict__ bb,
                                                float* __restrict__ h) {
    int t = blockIdx.x * 256 + threadIdx.x;
    int j = t & 31;
    const float inv_n = 1.0f / (float)NN;
    float mean = bns[j] * inv_n;
    float var = bns[32 + j] * inv_n - mean * mean;
    float sc = g[j] * rsqrtf(var + EPS);
    float sh = bb[j] - mean * sc;
    h[t] = fmaxf(y[t] * sc + sh, 0.f);
}

// ---------------- fp32 tiled GEMM: C = relu(A[M,K]@B[K,N] + bias) ----------------
#define GBM 64
#define GBN 64
#define GBK 16
__global__ __launch_bounds__(256) void k_gemm(const float* __restrict__ A, const float* __restrict__ Bm,
                                              const float* __restrict__ bias, float* __restrict__ C,
                                              int M, int Nc, int K, int relu) {
    __shared__ float As[GBK][GBM + 4];
    __shared__ float Bs[GBK][GBN + 4];
    int tid = threadIdx.x;
    int tx = tid & 15;
    int ty = tid >> 4;
    int rowBase = blockIdx.x * GBM;
    int colBase = blockIdx.y * GBN;
    int lr = tid >> 2;
    int lk = (tid & 3) * 4;
    int bkr = tid >> 4;
    int bc = (tid & 15) * 4;
    float acc[4][4] = {};
    for (int kt = 0; kt < K; kt += GBK) {
        float4 av = *(const float4*)(A + (size_t)(rowBase + lr) * K + kt + lk);
        As[lk + 0][lr] = av.x;
        As[lk + 1][lr] = av.y;
        As[lk + 2][lr] = av.z;
        As[lk + 3][lr] = av.w;
        float4 bv = *(const float4*)(Bm + (size_t)(kt + bkr) * Nc + colBase + bc);
        *(float4*)&Bs[bkr][bc] = bv;
        __syncthreads();
#pragma unroll
        for (int k = 0; k < GBK; ++k) {
            float4 ar = *(const float4*)&As[k][ty * 4];
            float4 br = *(const float4*)&Bs[k][tx * 4];
            acc[0][0] += ar.x * br.x; acc[0][1] += ar.x * br.y; acc[0][2] += ar.x * br.z; acc[0][3] += ar.x * br.w;
            acc[1][0] += ar.y * br.x; acc[1][1] += ar.y * br.y; acc[1][2] += ar.y * br.z; acc[1][3] += ar.y * br.w;
            acc[2][0] += ar.z * br.x; acc[2][1] += ar.z * br.y; acc[2][2] += ar.z * br.z; acc[2][3] += ar.z * br.w;
            acc[3][0] += ar.w * br.x; acc[3][1] += ar.w * br.y; acc[3][2] += ar.w * br.z; acc[3][3] += ar.w * br.w;
        }
        __syncthreads();
    }
    float b0 = bias[colBase + tx * 4 + 0];
    float b1 = bias[colBase + tx * 4 + 1];
    float b2 = bias[colBase + tx * 4 + 2];
    float b3 = bias[colBase + tx * 4 + 3];
#pragma unroll
    for (int i = 0; i < 4; ++i) {
        int row = rowBase + ty * 4 + i;
        float4 o;
        o.x = acc[i][0] + b0;
        o.y = acc[i][1] + b1;
        o.z = acc[i][2] + b2;
        o.w = acc[i][3] + b3;
        if (relu) {
            o.x = fmaxf(o.x, 0.f); o.y = fmaxf(o.y, 0.f);
            o.z = fmaxf(o.z, 0.f); o.w = fmaxf(o.w, 0.f);
        }
        *(float4*)(C + (size_t)row * Nc + colBase + tx * 4) = o;
    }
}

// ---------------- dueling head: value + adv - adv.mean ----------------
__global__ __launch_bounds__(64) void k_head(const float* __restrict__ X, const float* __restrict__ vW,
                                             const float* __restrict__ vb, const float* __restrict__ aW,
                                             const float* __restrict__ ab, float* __restrict__ out) {
    __shared__ float s[256];
    __shared__ float sval;
    int b = blockIdx.x, t = threadIdx.x;
    float4 xv = *(const float4*)(X + (size_t)b * 256 + t * 4);
    *(float4*)&s[t * 4] = xv;
    float pv = xv.x * vW[t * 4] + xv.y * vW[t * 4 + 1] + xv.z * vW[t * 4 + 2] + xv.w * vW[t * 4 + 3];
#pragma unroll
    for (int d = 32; d > 0; d >>= 1) pv += __shfl_down(pv, d, 64);
    if (t == 0) sval = pv + vb[0];
    __syncthreads();
    int n = t >> 1, a = t & 1;
    const float* wp = aW + n * 512 + a;
    float acc = 0.f;
#pragma unroll 8
    for (int f = 0; f < 256; ++f) acc += s[f] * wp[f * 2];
    float adv = acc + ab[n * 2 + a];
    float other = __shfl_xor(adv, 1, 64);
    out[(size_t)b * 64 + t] = sval + 0.5f * (adv - other);
}

extern "C" void kernel_launch(void* const* d_in, const int* in_sizes, int n_in,
                              void* d_out, int out_size, void* d_ws, size_t ws_size,
                              hipStream_t stream) {
    const float* x    = (const float*)d_in[0];
    const int*   ei   = (const int*)d_in[1];
    const float* c1W1 = (const float*)d_in[2];
    const float* c1b1 = (const float*)d_in[3];
    const float* c1W2 = (const float*)d_in[4];
    const float* c1b2 = (const float*)d_in[5];
    const float* c2W1 = (const float*)d_in[6];
    const float* c2b1 = (const float*)d_in[7];
    const float* c2W2 = (const float*)d_in[8];
    const float* c2b2 = (const float*)d_in[9];
    const float* c3W1 = (const float*)d_in[10];
    const float* c3b1 = (const float*)d_in[11];
    const float* c3W2 = (const float*)d_in[12];
    const float* c3b2 = (const float*)d_in[13];
    const float* bn_g = (const float*)d_in[14];
    const float* bn_b = (const float*)d_in[15];
    const float* mW1  = (const float*)d_in[16];
    const float* mb1  = (const float*)d_in[17];
    const float* mW2  = (const float*)d_in[18];
    const float* mb2  = (const float*)d_in[19];
    const float* mW3  = (const float*)d_in[20];
    const float* mb3  = (const float*)d_in[21];
    const float* vW   = (const float*)d_in[22];
    const float* vb   = (const float*)d_in[23];
    const float* aW   = (const float*)d_in[24];
    const float* ab   = (const float*)d_in[25];
    float* out = (float*)d_out;

    char* p = (char*)d_ws;
    auto take = [&](size_t bytes) {
        char* r = p;
        p += (bytes + 255) & ~(size_t)255;
        return r;
    };
    int*   gcount = (int*)take((size_t)BKT * 4);
    int*   words  = (int*)take((size_t)BKT * CAP * 4);          // ~10 MB bucketed edges
    float* u      = (float*)take((size_t)NN * HH * 4);
    float* v      = (float*)take((size_t)NN * HH * 4);
    float* y      = (float*)take((size_t)NN * SS * 4);
    float* h      = (float*)take((size_t)NN * SS * 4);
    float* bns    = (float*)take(3 * 64 * 4);
    // X1/X2 reuse the y buffer (dead after last bn_relu): 4096*256*4 = 4 MB each
    float* X1 = y;
    float* X2 = y + (size_t)BB * 256;

    hipMemsetAsync(gcount, 0, (size_t)BKT * 4, stream);
    hipMemsetAsync(bns, 0, 3 * 64 * 4, stream);

    // bucket partition (reused by all 3 conv layers)
    k_bsort<<<256, 256, 0, stream>>>(ei, gcount, words);

    // layer 1
    k_pre1<<<NN * 16 / 256, 256, 0, stream>>>(x, c1W1, c1b1, u, v);
    k_bgather<<<BKT, 512, 0, stream>>>(u, v, words, gcount, c1W2, c1b2, y);
    k_bnstat2<<<256, 256, 0, stream>>>(y, bns);
    k_bnrelu<<<NN * 32 / 256, 256, 0, stream>>>(y, bns, bn_g, bn_b, h);
    // layer 2
    k_pre32<<<NN / 16, 256, 0, stream>>>(h, c2W1, c2b1, u, v);
    k_bgather<<<BKT, 512, 0, stream>>>(u, v, words, gcount, c2W2, c2b2, y);
    k_bnstat2<<<256, 256, 0, stream>>>(y, bns + 64);
    k_bnrelu<<<NN * 32 / 256, 256, 0, stream>>>(y, bns + 64, bn_g + 32, bn_b + 32, h);
    // layer 3
    k_pre32<<<NN / 16, 256, 0, stream>>>(h, c3W1, c3b1, u, v);
    k_bgather<<<BKT, 512, 0, stream>>>(u, v, words, gcount, c3W2, c3b2, y);
    k_bnstat2<<<256, 256, 0, stream>>>(y, bns + 128);
    k_bnrelu<<<NN * 32 / 256, 256, 0, stream>>>(y, bns + 128, bn_g + 64, bn_b + 64, h);

    // dense head MLP (h is [4096,1024] row-major by construction)
    k_gemm<<<dim3(BB / GBM, 256 / GBN), 256, 0, stream>>>(h, mW1, mb1, X1, BB, 256, 1024, 1);
    k_gemm<<<dim3(BB / GBM, 256 / GBN), 256, 0, stream>>>(X1, mW2, mb2, X2, BB, 256, 256, 1);
    k_gemm<<<dim3(BB / GBM, 256 / GBN), 256, 0, stream>>>(X2, mW3, mb3, X1, BB, 256, 256, 1);

    // dueling heads
    k_head<<<BB, 64, 0, stream>>>(X1, vW, vb, aW, ab, out);
}

// Round 6
// 1010.342 us; speedup vs baseline: 1.0022x; 1.0022x over previous
//
#include <hip/hip_runtime.h>
#include <hip/hip_fp16.h>

#define NN 131072        // nodes
#define EE 2097152       // edges
#define SS 32            // channels
#define HH 16            // hidden
#define BB 4096          // graphs
#define EPS 1e-5f

#define BKT 512          // buckets (dst >> 8)
#define BNODES 256       // nodes per bucket
#define CAP 4864         // bucket capacity (avg 4096, +12 sigma)

typedef float vf4 __attribute__((ext_vector_type(4)));   // nontemporal-store-compatible

// ---------------- coarse bucket partition of edges by dst>>8 ----------------
__global__ __launch_bounds__(256) void k_bsort(const int* __restrict__ ei, int* __restrict__ gcount,
                                               int* __restrict__ words) {
    __shared__ int hist[BKT];
    __shared__ int base[BKT];
    int t = threadIdx.x;
    for (int i = t; i < BKT; i += 256) hist[i] = 0;
    __syncthreads();
    int e0 = blockIdx.x * 8192;
    for (int it = 0; it < 32; ++it) {
        int dst = ei[EE + e0 + it * 256 + t];
        atomicAdd(&hist[dst >> 8], 1);
    }
    __syncthreads();
    for (int i = t; i < BKT; i += 256) {
        base[i] = atomicAdd(&gcount[i], hist[i]);
        hist[i] = 0;                    // reuse as intra-tile cursor
    }
    __syncthreads();
    for (int it = 0; it < 32; ++it) {
        int e = e0 + it * 256 + t;
        int src = ei[e];
        int dst = ei[EE + e];
        int b = dst >> 8;
        int r = atomicAdd(&hist[b], 1);
        words[(size_t)b * CAP + base[b] + r] = src | ((dst & 255) << 17);
    }
}

// ---------------- per-node pre-transform (u = x@(Wt-Wb)+b1 fp32, v = x@Wb fp16) ------------
// v is fp16 so the whole array = 4 MB = one XCD's L2 (R4 lesson: fp32 v (8 MB)
// couldn't be L2-resident -> every XCD re-fetched all of v from HBM).
__global__ __launch_bounds__(256) void k_pre1(const float* __restrict__ x, const float* __restrict__ W1,
                                              const float* __restrict__ b1, float* __restrict__ u,
                                              __half* __restrict__ v) {
    int t = blockIdx.x * 256 + threadIdx.x;     // N*16 threads
    int n = t >> 4, c = t & 15;
    float x0 = x[n * 2], x1 = x[n * 2 + 1];
    float w0 = W1[c], w1 = W1[16 + c], w2 = W1[32 + c], w3 = W1[48 + c];
    u[t] = b1[c] + x0 * (w0 - w2) + x1 * (w1 - w3);
    v[t] = __float2half(x0 * w2 + x1 * w3);
}

// layers 2/3: F=32 input features
__global__ __launch_bounds__(256) void k_pre32(const float* __restrict__ h, const float* __restrict__ W1,
                                               const float* __restrict__ b1, float* __restrict__ u,
                                               __half* __restrict__ v) {
    __shared__ float sh[16][33];
    __shared__ float wd[32][16];
    __shared__ float wv[32][16];
    int t = threadIdx.x;
    for (int i = t; i < 512; i += 256) {
        int f = i >> 4, c = i & 15;
        float wt = W1[i];            // rows 0..31 (x_i part)
        float wb = W1[512 + i];      // rows 32..63 (x_j - x_i part)
        wd[f][c] = wt - wb;
        wv[f][c] = wb;
    }
    int nb = blockIdx.x * 16;
    for (int i = t; i < 512; i += 256) sh[i >> 5][i & 31] = h[nb * 32 + i];
    __syncthreads();
    int c = t & 15, nl = t >> 4;
    float uu = b1[c], vv = 0.f;
#pragma unroll
    for (int f = 0; f < 32; ++f) {
        float hv = sh[nl][f];
        uu += hv * wd[f][c];
        vv += hv * wv[f][c];
    }
    int n = nb + nl;
    u[n * 16 + c] = uu;
    v[n * 16 + c] = __float2half(vv);
}

// ---------------- bucketed gather: LDS-atomic reduce + @W2, one block per bucket ----------------
// All streaming traffic (words, u, y) is nontemporal so L2 stays reserved for v.
__global__ __launch_bounds__(512) void k_bgather(const float* __restrict__ u, const __half* __restrict__ v,
                                                 const int* __restrict__ words, const int* __restrict__ gcount,
                                                 const float* __restrict__ W2, const float* __restrict__ b2,
                                                 float* __restrict__ y) {
    __shared__ float uL[BNODES * 17];       // stride 17: conflict-free (17 coprime 32)
    __shared__ float agg[BNODES * 17];
    __shared__ int   cntL[BNODES];
    __shared__ float sW2[16 * 32];
    int t = threadIdx.x;
    int b = blockIdx.x;
    for (int i = t; i < 512; i += 512) sW2[i] = W2[i];
    for (int i = t; i < BNODES * 16; i += 512) {
        int nl = i >> 4, c = i & 15;
        uL[nl * 17 + c] = __builtin_nontemporal_load(u + (size_t)b * (BNODES * 16) + i);
        agg[nl * 17 + c] = 0.f;
    }
    for (int i = t; i < BNODES; i += 512) cntL[i] = 0;
    __syncthreads();

    int cnt = gcount[b];
    const int* wp = words + (size_t)b * CAP;
    int p = t;
    int w = (p < cnt) ? __builtin_nontemporal_load(wp + p) : 0;
    while (p < cnt) {
        int pn = p + 512;
        int wn = (pn < cnt) ? __builtin_nontemporal_load(wp + pn) : 0;   // prefetch next edge word
        int src = w & 0x1FFFF;
        int dl = w >> 17;
        const float4* vp = (const float4*)(v + (size_t)src * 16);        // 32 B fp16 row
        float4 ra = vp[0], rb = vp[1];
        float vv[16];
        {
            const __half2* pa = (const __half2*)&ra;
            const __half2* pb = (const __half2*)&rb;
#pragma unroll
            for (int i = 0; i < 4; ++i) {
                float2 f = __half22float2(pa[i]);
                vv[2 * i] = f.x; vv[2 * i + 1] = f.y;
            }
#pragma unroll
            for (int i = 0; i < 4; ++i) {
                float2 f = __half22float2(pb[i]);
                vv[8 + 2 * i] = f.x; vv[8 + 2 * i + 1] = f.y;
            }
        }
        atomicAdd(&cntL[dl], 1);
        float* ub = &uL[dl * 17];
        float* ab = &agg[dl * 17];
#pragma unroll
        for (int c = 0; c < 16; ++c) atomicAdd(&ab[c], fmaxf(ub[c] + vv[c], 0.f));
        p = pn;
        w = wn;
    }
    __syncthreads();

    // epilogue: 2 threads per node, 16 output channels each
    int nl = t >> 1;
    int half = (t & 1) * 16;
    float cw = (float)cntL[nl];
    float o[16];
#pragma unroll
    for (int c = 0; c < 16; ++c) o[c] = b2[half + c] * cw;
#pragma unroll
    for (int k = 0; k < 16; ++k) {
        float a = agg[nl * 17 + k];
#pragma unroll
        for (int c = 0; c < 16; ++c) o[c] += a * sW2[k * 32 + half + c];
    }
    float* yp = y + (size_t)b * (BNODES * 32) + nl * 32 + half;
#pragma unroll
    for (int c = 0; c < 16; c += 4) {
        vf4 ov = { o[c], o[c + 1], o[c + 2], o[c + 3] };
        __builtin_nontemporal_store(ov, (vf4*)(yp + c));
    }
}

// ---------------- BN stats straight from y: 256 blocks x 512 rows ----------------
__global__ __launch_bounds__(256) void k_bnstat2(const float* __restrict__ y, float* __restrict__ bns) {
    __shared__ float ssm[8][33];
    __shared__ float ssq[8][33];
    int t = threadIdx.x;
    int c = t & 31, g = t >> 5;             // 8 row-groups
    size_t r0 = (size_t)blockIdx.x * 512;
    float sm = 0.f, sq = 0.f;
    for (int i = 0; i < 64; ++i) {
        float val = y[(r0 + g + (size_t)i * 8) * 32 + c];
        sm += val;
        sq += val * val;
    }
    ssm[g][c] = sm;
    ssq[g][c] = sq;
    __syncthreads();
    if (t < 32) {
        float a = 0.f, bq = 0.f;
#pragma unroll
        for (int gg = 0; gg < 8; ++gg) { a += ssm[gg][t]; bq += ssq[gg][t]; }
        atomicAdd(&bns[t], a);
        atomicAdd(&bns[32 + t], bq);
    }
}

// ---------------- BN (training-mode batch stats) + ReLU ----------------
__global__ __launch_bounds__(256) void k_bnrelu(const float* __restrict__ y, const float* __restrict__ bns,
                                                const float* __restrict__ g, const float* __restrict__ bb,
                                                float* __restrict__ h) {
    int t = blockIdx.x * 256 + threadIdx.x;
    int j = t & 31;
    const float inv_n = 1.0f / (float)NN;
    float mean = bns[j] * inv_n;
    float var = bns[32 + j] * inv_n - mean * mean;
    float sc = g[j] * rsqrtf(var + EPS);
    float sh = bb[j] - mean * sc;
    h[t] = fmaxf(y[t] * sc + sh, 0.f);
}

// ---------------- fp32 tiled GEMM: C = relu(A[M,K]@B[K,N] + bias) ----------------
#define GBM 64
#define GBN 64
#define GBK 16
__global__ __launch_bounds__(256) void k_gemm(const float* __restrict__ A, const float* __restrict__ Bm,
                                              const float* __restrict__ bias, float* __restrict__ C,
                                              int M, int Nc, int K, int relu) {
    __shared__ float As[GBK][GBM + 4];
    __shared__ float Bs[GBK][GBN + 4];
    int tid = threadIdx.x;
    int tx = tid & 15;
    int ty = tid >> 4;
    int rowBase = blockIdx.x * GBM;
    int colBase = blockIdx.y * GBN;
    int lr = tid >> 2;
    int lk = (tid & 3) * 4;
    int bkr = tid >> 4;
    int bc = (tid & 15) * 4;
    float acc[4][4] = {};
    for (int kt = 0; kt < K; kt += GBK) {
        float4 av = *(const float4*)(A + (size_t)(rowBase + lr) * K + kt + lk);
        As[lk + 0][lr] = av.x;
        As[lk + 1][lr] = av.y;
        As[lk + 2][lr] = av.z;
        As[lk + 3][lr] = av.w;
        float4 bv = *(const float4*)(Bm + (size_t)(kt + bkr) * Nc + colBase + bc);
        *(float4*)&Bs[bkr][bc] = bv;
        __syncthreads();
#pragma unroll
        for (int k = 0; k < GBK; ++k) {
            float4 ar = *(const float4*)&As[k][ty * 4];
            float4 br = *(const float4*)&Bs[k][tx * 4];
            acc[0][0] += ar.x * br.x; acc[0][1] += ar.x * br.y; acc[0][2] += ar.x * br.z; acc[0][3] += ar.x * br.w;
            acc[1][0] += ar.y * br.x; acc[1][1] += ar.y * br.y; acc[1][2] += ar.y * br.z; acc[1][3] += ar.y * br.w;
            acc[2][0] += ar.z * br.x; acc[2][1] += ar.z * br.y; acc[2][2] += ar.z * br.z; acc[2][3] += ar.z * br.w;
            acc[3][0] += ar.w * br.x; acc[3][1] += ar.w * br.y; acc[3][2] += ar.w * br.z; acc[3][3] += ar.w * br.w;
        }
        __syncthreads();
    }
    float b0 = bias[colBase + tx * 4 + 0];
    float b1 = bias[colBase + tx * 4 + 1];
    float b2 = bias[colBase + tx * 4 + 2];
    float b3 = bias[colBase + tx * 4 + 3];
#pragma unroll
    for (int i = 0; i < 4; ++i) {
        int row = rowBase + ty * 4 + i;
        float4 o;
        o.x = acc[i][0] + b0;
        o.y = acc[i][1] + b1;
        o.z = acc[i][2] + b2;
        o.w = acc[i][3] + b3;
        if (relu) {
            o.x = fmaxf(o.x, 0.f); o.y = fmaxf(o.y, 0.f);
            o.z = fmaxf(o.z, 0.f); o.w = fmaxf(o.w, 0.f);
        }
        *(float4*)(C + (size_t)row * Nc + colBase + tx * 4) = o;
    }
}

// ---------------- dueling head: value + adv - adv.mean ----------------
__global__ __launch_bounds__(64) void k_head(const float* __restrict__ X, const float* __restrict__ vW,
                                             const float* __restrict__ vb, const float* __restrict__ aW,
                                             const float* __restrict__ ab, float* __restrict__ out) {
    __shared__ float s[256];
    __shared__ float sval;
    int b = blockIdx.x, t = threadIdx.x;
    float4 xv = *(const float4*)(X + (size_t)b * 256 + t * 4);
    *(float4*)&s[t * 4] = xv;
    float pv = xv.x * vW[t * 4] + xv.y * vW[t * 4 + 1] + xv.z * vW[t * 4 + 2] + xv.w * vW[t * 4 + 3];
#pragma unroll
    for (int d = 32; d > 0; d >>= 1) pv += __shfl_down(pv, d, 64);
    if (t == 0) sval = pv + vb[0];
    __syncthreads();
    int n = t >> 1, a = t & 1;
    const float* wp = aW + n * 512 + a;
    float acc = 0.f;
#pragma unroll 8
    for (int f = 0; f < 256; ++f) acc += s[f] * wp[f * 2];
    float adv = acc + ab[n * 2 + a];
    float other = __shfl_xor(adv, 1, 64);
    out[(size_t)b * 64 + t] = sval + 0.5f * (adv - other);
}

extern "C" void kernel_launch(void* const* d_in, const int* in_sizes, int n_in,
                              void* d_out, int out_size, void* d_ws, size_t ws_size,
                              hipStream_t stream) {
    const float* x    = (const float*)d_in[0];
    const int*   ei   = (const int*)d_in[1];
    const float* c1W1 = (const float*)d_in[2];
    const float* c1b1 = (const float*)d_in[3];
    const float* c1W2 = (const float*)d_in[4];
    const float* c1b2 = (const float*)d_in[5];
    const float* c2W1 = (const float*)d_in[6];
    const float* c2b1 = (const float*)d_in[7];
    const float* c2W2 = (const float*)d_in[8];
    const float* c2b2 = (const float*)d_in[9];
    const float* c3W1 = (const float*)d_in[10];
    const float* c3b1 = (const float*)d_in[11];
    const float* c3W2 = (const float*)d_in[12];
    const float* c3b2 = (const float*)d_in[13];
    const float* bn_g = (const float*)d_in[14];
    const float* bn_b = (const float*)d_in[15];
    const float* mW1  = (const float*)d_in[16];
    const float* mb1  = (const float*)d_in[17];
    const float* mW2  = (const float*)d_in[18];
    const float* mb2  = (const float*)d_in[19];
    const float* mW3  = (const float*)d_in[20];
    const float* mb3  = (const float*)d_in[21];
    const float* vW   = (const float*)d_in[22];
    const float* vb   = (const float*)d_in[23];
    const float* aW   = (const float*)d_in[24];
    const float* ab   = (const float*)d_in[25];
    float* out = (float*)d_out;

    char* p = (char*)d_ws;
    auto take = [&](size_t bytes) {
        char* r = p;
        p += (bytes + 255) & ~(size_t)255;
        return r;
    };
    int*    gcount = (int*)take((size_t)BKT * 4);
    int*    words  = (int*)take((size_t)BKT * CAP * 4);          // ~10 MB bucketed edges
    float*  u      = (float*)take((size_t)NN * HH * 4);
    __half* v      = (__half*)take((size_t)NN * HH * 2);         // 4 MB (= one XCD L2)
    float*  y      = (float*)take((size_t)NN * SS * 4);
    float*  h      = (float*)take((size_t)NN * SS * 4);
    float*  bns    = (float*)take(3 * 64 * 4);
    // X1/X2 reuse the y buffer (dead after last bn_relu): 4096*256*4 = 4 MB each
    float* X1 = y;
    float* X2 = y + (size_t)BB * 256;

    (void)hipMemsetAsync(gcount, 0, (size_t)BKT * 4, stream);
    (void)hipMemsetAsync(bns, 0, 3 * 64 * 4, stream);

    // bucket partition (reused by all 3 conv layers)
    k_bsort<<<256, 256, 0, stream>>>(ei, gcount, words);

    // layer 1
    k_pre1<<<NN * 16 / 256, 256, 0, stream>>>(x, c1W1, c1b1, u, v);
    k_bgather<<<BKT, 512, 0, stream>>>(u, v, words, gcount, c1W2, c1b2, y);
    k_bnstat2<<<256, 256, 0, stream>>>(y, bns);
    k_bnrelu<<<NN * 32 / 256, 256, 0, stream>>>(y, bns, bn_g, bn_b, h);
    // layer 2
    k_pre32<<<NN / 16, 256, 0, stream>>>(h, c2W1, c2b1, u, v);
    k_bgather<<<BKT, 512, 0, stream>>>(u, v, words, gcount, c2W2, c2b2, y);
    k_bnstat2<<<256, 256, 0, stream>>>(y, bns + 64);
    k_bnrelu<<<NN * 32 / 256, 256, 0, stream>>>(y, bns + 64, bn_g + 32, bn_b + 32, h);
    // layer 3
    k_pre32<<<NN / 16, 256, 0, stream>>>(h, c3W1, c3b1, u, v);
    k_bgather<<<BKT, 512, 0, stream>>>(u, v, words, gcount, c3W2, c3b2, y);
    k_bnstat2<<<256, 256, 0, stream>>>(y, bns + 128);
    k_bnrelu<<<NN * 32 / 256, 256, 0, stream>>>(y, bns + 128, bn_g + 64, bn_b + 64, h);

    // dense head MLP (h is [4096,1024] row-major by construction)
    k_gemm<<<dim3(BB / GBM, 256 / GBN), 256, 0, stream>>>(h, mW1, mb1, X1, BB, 256, 1024, 1);
    k_gemm<<<dim3(BB / GBM, 256 / GBN), 256, 0, stream>>>(X1, mW2, mb2, X2, BB, 256, 256, 1);
    k_gemm<<<dim3(BB / GBM, 256 / GBN), 256, 0, stream>>>(X2, mW3, mb3, X1, BB, 256, 256, 1);

    // dueling heads
    k_head<<<BB, 64, 0, stream>>>(X1, vW, vb, aW, ab, out);
}

// Round 7
// 598.559 us; speedup vs baseline: 1.6917x; 1.6880x over previous
//
#include <hip/hip_runtime.h>
#include <hip/hip_fp16.h>

#define NN 131072        // nodes
#define EE 2097152       // edges
#define SS 32            // channels
#define HH 16            // hidden
#define BB 4096          // graphs
#define EPS 1e-5f

#define BKT 512          // buckets (dst >> 8)
#define BNODES 256       // nodes per bucket
#define CAP 4864         // bucket capacity (avg 4096, +12 sigma)

// ---------------- coarse bucket partition of edges by dst>>8 ----------------
__global__ __launch_bounds__(256) void k_bsort(const int* __restrict__ ei, int* __restrict__ gcount,
                                               int* __restrict__ words) {
    __shared__ int hist[BKT];
    __shared__ int base[BKT];
    int t = threadIdx.x;
    for (int i = t; i < BKT; i += 256) hist[i] = 0;
    __syncthreads();
    int e0 = blockIdx.x * 8192;
    for (int it = 0; it < 32; ++it) {
        int dst = ei[EE + e0 + it * 256 + t];
        atomicAdd(&hist[dst >> 8], 1);
    }
    __syncthreads();
    for (int i = t; i < BKT; i += 256) {
        base[i] = atomicAdd(&gcount[i], hist[i]);
        hist[i] = 0;                    // reuse as intra-tile cursor
    }
    __syncthreads();
    for (int it = 0; it < 32; ++it) {
        int e = e0 + it * 256 + t;
        int src = ei[e];
        int dst = ei[EE + e];
        int b = dst >> 8;
        int r = atomicAdd(&hist[b], 1);
        words[(size_t)b * CAP + base[b] + r] = src | ((dst & 255) << 17);
    }
}

// ---------------- within-bucket sort to exact CSR (one block per bucket) ----------------
// Bucket data is L2-resident (just written). Histogram 256 nodes -> scan -> scatter.
__global__ __launch_bounds__(256) void k_csr(const int* __restrict__ words, const int* __restrict__ gcount,
                                             int* __restrict__ ssrc, int* __restrict__ offs,
                                             int* __restrict__ offe) {
    __shared__ int hist[BNODES];
    __shared__ int sc[BNODES];
    __shared__ int base[BNODES];
    int t = threadIdx.x;
    int b = blockIdx.x;
    hist[t] = 0;
    __syncthreads();
    int cnt = gcount[b];
    const int* wp = words + (size_t)b * CAP;
    for (int p = t; p < cnt; p += 256) atomicAdd(&hist[wp[p] >> 17], 1);
    __syncthreads();
    int val = hist[t];
    sc[t] = val;
    __syncthreads();
    for (int d = 1; d < 256; d <<= 1) {
        int v2 = (t >= d) ? sc[t - d] : 0;
        __syncthreads();
        sc[t] += v2;
        __syncthreads();
    }
    base[t] = sc[t] - val;              // exclusive scan
    int gbase = b * CAP;
    offs[b * BNODES + t] = gbase + base[t];
    offe[b * BNODES + t] = gbase + sc[t];
    __syncthreads();
    hist[t] = 0;                        // reuse as per-node cursor
    __syncthreads();
    for (int p = t; p < cnt; p += 256) {
        int w = wp[p];
        int dl = w >> 17;
        int r = atomicAdd(&hist[dl], 1);
        ssrc[gbase + base[dl] + r] = w & 0x1FFFF;
    }
}

// ---------------- per-node pre-transform (u = x@(Wt-Wb)+b1 fp32, v = x@Wb fp16) ------------
// v fp16: whole array = 4 MB => L2-resident (R6). Row NN is a large-negative dummy so
// padded gather slots contribute 0 after ReLU.
__global__ __launch_bounds__(256) void k_pre1(const float* __restrict__ x, const float* __restrict__ W1,
                                              const float* __restrict__ b1, float* __restrict__ u,
                                              __half* __restrict__ v) {
    int t = blockIdx.x * 256 + threadIdx.x;     // N*16 threads
    int n = t >> 4, c = t & 15;
    float x0 = x[n * 2], x1 = x[n * 2 + 1];
    float w0 = W1[c], w1 = W1[16 + c], w2 = W1[32 + c], w3 = W1[48 + c];
    u[t] = b1[c] + x0 * (w0 - w2) + x1 * (w1 - w3);
    v[t] = __float2half(x0 * w2 + x1 * w3);
    if (blockIdx.x == 0 && t < 16) v[NN * 16 + t] = __float2half(-60000.0f);
}

// layers 2/3: F=32 input features
__global__ __launch_bounds__(256) void k_pre32(const float* __restrict__ h, const float* __restrict__ W1,
                                               const float* __restrict__ b1, float* __restrict__ u,
                                               __half* __restrict__ v) {
    __shared__ float sh[16][33];
    __shared__ float wd[32][16];
    __shared__ float wv[32][16];
    int t = threadIdx.x;
    for (int i = t; i < 512; i += 256) {
        int f = i >> 4, c = i & 15;
        float wt = W1[i];            // rows 0..31 (x_i part)
        float wb = W1[512 + i];      // rows 32..63 (x_j - x_i part)
        wd[f][c] = wt - wb;
        wv[f][c] = wb;
    }
    int nb = blockIdx.x * 16;
    for (int i = t; i < 512; i += 256) sh[i >> 5][i & 31] = h[nb * 32 + i];
    __syncthreads();
    int c = t & 15, nl = t >> 4;
    float uu = b1[c], vv = 0.f;
#pragma unroll
    for (int f = 0; f < 32; ++f) {
        float hv = sh[nl][f];
        uu += hv * wd[f][c];
        vv += hv * wv[f][c];
    }
    int n = nb + nl;
    u[n * 16 + c] = uu;
    v[n * 16 + c] = __float2half(vv);
    if (blockIdx.x == 0 && t < 16) v[NN * 16 + t] = __float2half(-60000.0f);
}

// ---------------- CSR gather (register acc, 8-wide MLP) + @W2 ----------------
// R2/R3-proven structure: 8192 blocks, VGPR~32 => high occupancy hides gather latency.
__global__ __launch_bounds__(256) void k_gather(const float* __restrict__ u, const __half* __restrict__ v,
                                                const int* __restrict__ ssrc, const int* __restrict__ offs,
                                                const int* __restrict__ offe,
                                                const float* __restrict__ W2, const float* __restrict__ b2,
                                                float* __restrict__ y) {
    __shared__ float sw2[16][32];
    __shared__ float sagg[16][17];
    int t = threadIdx.x;
    for (int i = t; i < 512; i += 256) sw2[i >> 5][i & 31] = W2[i];
    int c = t & 15, nl = t >> 4;
    int n = blockIdx.x * 16 + nl;
    int s0 = offs[n], e0 = offe[n];
    float uc = u[n * 16 + c];
    float acc = 0.f;
    for (int p = s0; p < e0; p += 8) {
        int idx[8];
#pragma unroll
        for (int i = 0; i < 8; ++i) idx[i] = (p + i < e0) ? ssrc[p + i] : NN;
        float vv[8];
#pragma unroll
        for (int i = 0; i < 8; ++i) vv[i] = __half2float(v[(size_t)idx[i] * 16 + c]);
#pragma unroll
        for (int i = 0; i < 8; ++i) acc += fmaxf(uc + vv[i], 0.f);
    }
    sagg[nl][c] = acc;
    __syncthreads();
    float cnt = (float)(e0 - s0);
    float y0 = b2[c] * cnt, y1 = b2[c + 16] * cnt;
#pragma unroll
    for (int k = 0; k < 16; ++k) {
        float a = sagg[nl][k];
        y0 += a * sw2[k][c];
        y1 += a * sw2[k][c + 16];
    }
    y[n * 32 + c] = y0;
    y[n * 32 + 16 + c] = y1;
}

// ---------------- BN stats straight from y: 256 blocks x 512 rows ----------------
__global__ __launch_bounds__(256) void k_bnstat2(const float* __restrict__ y, float* __restrict__ bns) {
    __shared__ float ssm[8][33];
    __shared__ float ssq[8][33];
    int t = threadIdx.x;
    int c = t & 31, g = t >> 5;             // 8 row-groups
    size_t r0 = (size_t)blockIdx.x * 512;
    float sm = 0.f, sq = 0.f;
    for (int i = 0; i < 64; ++i) {
        float val = y[(r0 + g + (size_t)i * 8) * 32 + c];
        sm += val;
        sq += val * val;
    }
    ssm[g][c] = sm;
    ssq[g][c] = sq;
    __syncthreads();
    if (t < 32) {
        float a = 0.f, bq = 0.f;
#pragma unroll
        for (int gg = 0; gg < 8; ++gg) { a += ssm[gg][t]; bq += ssq[gg][t]; }
        atomicAdd(&bns[t], a);
        atomicAdd(&bns[32 + t], bq);
    }
}

// ---------------- BN (training-mode batch stats) + ReLU ----------------
__global__ __launch_bounds__(256) void k_bnrelu(const float* __restrict__ y, const float* __restrict__ bns,
                                                const float* __restrict__ g, const float* __restrict__ bb,
                                                float* __restrict__ h) {
    int t = blockIdx.x * 256 + threadIdx.x;
    int j = t & 31;
    const float inv_n = 1.0f / (float)NN;
    float mean = bns[j] * inv_n;
    float var = bns[32 + j] * inv_n - mean * mean;
    float sc = g[j] * rsqrtf(var + EPS);
    float sh = bb[j] - mean * sc;
    h[t] = fmaxf(y[t] * sc + sh, 0.f);
}

// ---------------- fp32 tiled GEMM: C = relu(A[M,K]@B[K,N] + bias) ----------------
#define GBM 64
#define GBN 64
#define GBK 16
__global__ __launch_bounds__(256) void k_gemm(const float* __restrict__ A, const float* __restrict__ Bm,
                                              const float* __restrict__ bias, float* __restrict__ C,
                                              int M, int Nc, int K, int relu) {
    __shared__ float As[GBK][GBM + 4];
    __shared__ float Bs[GBK][GBN + 4];
    int tid = threadIdx.x;
    int tx = tid & 15;
    int ty = tid >> 4;
    int rowBase = blockIdx.x * GBM;
    int colBase = blockIdx.y * GBN;
    int lr = tid >> 2;
    int lk = (tid & 3) * 4;
    int bkr = tid >> 4;
    int bc = (tid & 15) * 4;
    float acc[4][4] = {};
    for (int kt = 0; kt < K; kt += GBK) {
        float4 av = *(const float4*)(A + (size_t)(rowBase + lr) * K + kt + lk);
        As[lk + 0][lr] = av.x;
        As[lk + 1][lr] = av.y;
        As[lk + 2][lr] = av.z;
        As[lk + 3][lr] = av.w;
        float4 bv = *(const float4*)(Bm + (size_t)(kt + bkr) * Nc + colBase + bc);
        *(float4*)&Bs[bkr][bc] = bv;
        __syncthreads();
#pragma unroll
        for (int k = 0; k < GBK; ++k) {
            float4 ar = *(const float4*)&As[k][ty * 4];
            float4 br = *(const float4*)&Bs[k][tx * 4];
            acc[0][0] += ar.x * br.x; acc[0][1] += ar.x * br.y; acc[0][2] += ar.x * br.z; acc[0][3] += ar.x * br.w;
            acc[1][0] += ar.y * br.x; acc[1][1] += ar.y * br.y; acc[1][2] += ar.y * br.z; acc[1][3] += ar.y * br.w;
            acc[2][0] += ar.z * br.x; acc[2][1] += ar.z * br.y; acc[2][2] += ar.z * br.z; acc[2][3] += ar.z * br.w;
            acc[3][0] += ar.w * br.x; acc[3][1] += ar.w * br.y; acc[3][2] += ar.w * br.z; acc[3][3] += ar.w * br.w;
        }
        __syncthreads();
    }
    float b0 = bias[colBase + tx * 4 + 0];
    float b1 = bias[colBase + tx * 4 + 1];
    float b2 = bias[colBase + tx * 4 + 2];
    float b3 = bias[colBase + tx * 4 + 3];
#pragma unroll
    for (int i = 0; i < 4; ++i) {
        int row = rowBase + ty * 4 + i;
        float4 o;
        o.x = acc[i][0] + b0;
        o.y = acc[i][1] + b1;
        o.z = acc[i][2] + b2;
        o.w = acc[i][3] + b3;
        if (relu) {
            o.x = fmaxf(o.x, 0.f); o.y = fmaxf(o.y, 0.f);
            o.z = fmaxf(o.z, 0.f); o.w = fmaxf(o.w, 0.f);
        }
        *(float4*)(C + (size_t)row * Nc + colBase + tx * 4) = o;
    }
}

// ---------------- dueling head: value + adv - adv.mean ----------------
__global__ __launch_bounds__(64) void k_head(const float* __restrict__ X, const float* __restrict__ vW,
                                             const float* __restrict__ vb, const float* __restrict__ aW,
                                             const float* __restrict__ ab, float* __restrict__ out) {
    __shared__ float s[256];
    __shared__ float sval;
    int b = blockIdx.x, t = threadIdx.x;
    float4 xv = *(const float4*)(X + (size_t)b * 256 + t * 4);
    *(float4*)&s[t * 4] = xv;
    float pv = xv.x * vW[t * 4] + xv.y * vW[t * 4 + 1] + xv.z * vW[t * 4 + 2] + xv.w * vW[t * 4 + 3];
#pragma unroll
    for (int d = 32; d > 0; d >>= 1) pv += __shfl_down(pv, d, 64);
    if (t == 0) sval = pv + vb[0];
    __syncthreads();
    int n = t >> 1, a = t & 1;
    const float* wp = aW + n * 512 + a;
    float acc = 0.f;
#pragma unroll 8
    for (int f = 0; f < 256; ++f) acc += s[f] * wp[f * 2];
    float adv = acc + ab[n * 2 + a];
    float other = __shfl_xor(adv, 1, 64);
    out[(size_t)b * 64 + t] = sval + 0.5f * (adv - other);
}

extern "C" void kernel_launch(void* const* d_in, const int* in_sizes, int n_in,
                              void* d_out, int out_size, void* d_ws, size_t ws_size,
                              hipStream_t stream) {
    const float* x    = (const float*)d_in[0];
    const int*   ei   = (const int*)d_in[1];
    const float* c1W1 = (const float*)d_in[2];
    const float* c1b1 = (const float*)d_in[3];
    const float* c1W2 = (const float*)d_in[4];
    const float* c1b2 = (const float*)d_in[5];
    const float* c2W1 = (const float*)d_in[6];
    const float* c2b1 = (const float*)d_in[7];
    const float* c2W2 = (const float*)d_in[8];
    const float* c2b2 = (const float*)d_in[9];
    const float* c3W1 = (const float*)d_in[10];
    const float* c3b1 = (const float*)d_in[11];
    const float* c3W2 = (const float*)d_in[12];
    const float* c3b2 = (const float*)d_in[13];
    const float* bn_g = (const float*)d_in[14];
    const float* bn_b = (const float*)d_in[15];
    const float* mW1  = (const float*)d_in[16];
    const float* mb1  = (const float*)d_in[17];
    const float* mW2  = (const float*)d_in[18];
    const float* mb2  = (const float*)d_in[19];
    const float* mW3  = (const float*)d_in[20];
    const float* mb3  = (const float*)d_in[21];
    const float* vW   = (const float*)d_in[22];
    const float* vb   = (const float*)d_in[23];
    const float* aW   = (const float*)d_in[24];
    const float* ab   = (const float*)d_in[25];
    float* out = (float*)d_out;

    char* p = (char*)d_ws;
    auto take = [&](size_t bytes) {
        char* r = p;
        p += (bytes + 255) & ~(size_t)255;
        return r;
    };
    int*    gcount = (int*)take((size_t)BKT * 4);
    int*    words  = (int*)take((size_t)BKT * CAP * 4);          // ~10 MB bucketed edges
    int*    ssrc   = (int*)take((size_t)BKT * CAP * 4);          // ~10 MB CSR-ordered srcs
    int*    offs   = (int*)take((size_t)NN * 4);
    int*    offe   = (int*)take((size_t)NN * 4);
    float*  u      = (float*)take((size_t)NN * HH * 4);
    __half* v      = (__half*)take((size_t)(NN + 1) * HH * 2);   // 4 MB (= one XCD L2) + dummy row
    float*  y      = (float*)take((size_t)NN * SS * 4);
    float*  h      = (float*)take((size_t)NN * SS * 4);
    float*  bns    = (float*)take(3 * 64 * 4);
    // X1/X2 reuse the y buffer (dead after last bn_relu): 4096*256*4 = 4 MB each
    float* X1 = y;
    float* X2 = y + (size_t)BB * 256;

    (void)hipMemsetAsync(gcount, 0, (size_t)BKT * 4, stream);
    (void)hipMemsetAsync(bns, 0, 3 * 64 * 4, stream);

    // CSR build: coarse bucket partition, then within-bucket sort (reused by all 3 layers)
    k_bsort<<<256, 256, 0, stream>>>(ei, gcount, words);
    k_csr<<<BKT, 256, 0, stream>>>(words, gcount, ssrc, offs, offe);

    // layer 1
    k_pre1<<<NN * 16 / 256, 256, 0, stream>>>(x, c1W1, c1b1, u, v);
    k_gather<<<NN / 16, 256, 0, stream>>>(u, v, ssrc, offs, offe, c1W2, c1b2, y);
    k_bnstat2<<<256, 256, 0, stream>>>(y, bns);
    k_bnrelu<<<NN * 32 / 256, 256, 0, stream>>>(y, bns, bn_g, bn_b, h);
    // layer 2
    k_pre32<<<NN / 16, 256, 0, stream>>>(h, c2W1, c2b1, u, v);
    k_gather<<<NN / 16, 256, 0, stream>>>(u, v, ssrc, offs, offe, c2W2, c2b2, y);
    k_bnstat2<<<256, 256, 0, stream>>>(y, bns + 64);
    k_bnrelu<<<NN * 32 / 256, 256, 0, stream>>>(y, bns + 64, bn_g + 32, bn_b + 32, h);
    // layer 3
    k_pre32<<<NN / 16, 256, 0, stream>>>(h, c3W1, c3b1, u, v);
    k_gather<<<NN / 16, 256, 0, stream>>>(u, v, ssrc, offs, offe, c3W2, c3b2, y);
    k_bnstat2<<<256, 256, 0, stream>>>(y, bns + 128);
    k_bnrelu<<<NN * 32 / 256, 256, 0, stream>>>(y, bns + 128, bn_g + 64, bn_b + 64, h);

    // dense head MLP (h is [4096,1024] row-major by construction)
    k_gemm<<<dim3(BB / GBM, 256 / GBN), 256, 0, stream>>>(h, mW1, mb1, X1, BB, 256, 1024, 1);
    k_gemm<<<dim3(BB / GBM, 256 / GBN), 256, 0, stream>>>(X1, mW2, mb2, X2, BB, 256, 256, 1);
    k_gemm<<<dim3(BB / GBM, 256 / GBN), 256, 0, stream>>>(X2, mW3, mb3, X1, BB, 256, 256, 1);

    // dueling heads
    k_head<<<BB, 64, 0, stream>>>(X1, vW, vb, aW, ab, out);
}

// Round 8
// 499.656 us; speedup vs baseline: 2.0265x; 1.1979x over previous
//
#include <hip/hip_runtime.h>
#include <hip/hip_fp16.h>

#define NN 131072        // nodes
#define EE 2097152       // edges
#define SS 32            // channels
#define HH 16            // hidden
#define BB 4096          // graphs
#define EPS 1e-5f

#define BKT 512          // buckets (dst >> 8)
#define BNODES 256       // nodes per bucket
#define CAP 4864         // bucket capacity (avg 4096, +12 sigma)

// ---------------- coarse bucket partition of edges by dst>>8 ----------------
__global__ __launch_bounds__(256) void k_bsort(const int* __restrict__ ei, int* __restrict__ gcount,
                                               int* __restrict__ words) {
    __shared__ int hist[BKT];
    __shared__ int base[BKT];
    int t = threadIdx.x;
    for (int i = t; i < BKT; i += 256) hist[i] = 0;
    __syncthreads();
    int e0 = blockIdx.x * 8192;
    for (int it = 0; it < 32; ++it) {
        int dst = ei[EE + e0 + it * 256 + t];
        atomicAdd(&hist[dst >> 8], 1);
    }
    __syncthreads();
    for (int i = t; i < BKT; i += 256) {
        base[i] = atomicAdd(&gcount[i], hist[i]);
        hist[i] = 0;                    // reuse as intra-tile cursor
    }
    __syncthreads();
    for (int it = 0; it < 32; ++it) {
        int e = e0 + it * 256 + t;
        int src = ei[e];
        int dst = ei[EE + e];
        int b = dst >> 8;
        int r = atomicAdd(&hist[b], 1);
        words[(size_t)b * CAP + base[b] + r] = src | ((dst & 255) << 17);
    }
}

// ---------------- within-bucket sort to exact CSR (one block per bucket) ----------------
__global__ __launch_bounds__(256) void k_csr(const int* __restrict__ words, const int* __restrict__ gcount,
                                             int* __restrict__ ssrc, int* __restrict__ offs,
                                             int* __restrict__ offe) {
    __shared__ int hist[BNODES];
    __shared__ int sc[BNODES];
    __shared__ int base[BNODES];
    int t = threadIdx.x;
    int b = blockIdx.x;
    hist[t] = 0;
    __syncthreads();
    int cnt = gcount[b];
    const int* wp = words + (size_t)b * CAP;
    for (int p = t; p < cnt; p += 256) atomicAdd(&hist[wp[p] >> 17], 1);
    __syncthreads();
    int val = hist[t];
    sc[t] = val;
    __syncthreads();
    for (int d = 1; d < 256; d <<= 1) {
        int v2 = (t >= d) ? sc[t - d] : 0;
        __syncthreads();
        sc[t] += v2;
        __syncthreads();
    }
    base[t] = sc[t] - val;              // exclusive scan
    int gbase = b * CAP;
    offs[b * BNODES + t] = gbase + base[t];
    offe[b * BNODES + t] = gbase + sc[t];
    __syncthreads();
    hist[t] = 0;                        // reuse as per-node cursor
    __syncthreads();
    for (int p = t; p < cnt; p += 256) {
        int w = wp[p];
        int dl = w >> 17;
        int r = atomicAdd(&hist[dl], 1);
        ssrc[gbase + base[dl] + r] = w & 0x1FFFF;
    }
}

// ---------------- per-node pre-transform (u = x@(Wt-Wb)+b1 fp32, v = x@Wb fp16) ------------
__global__ __launch_bounds__(256) void k_pre1(const float* __restrict__ x, const float* __restrict__ W1,
                                              const float* __restrict__ b1, float* __restrict__ u,
                                              __half* __restrict__ v) {
    int t = blockIdx.x * 256 + threadIdx.x;     // N*16 threads
    int n = t >> 4, c = t & 15;
    float x0 = x[n * 2], x1 = x[n * 2 + 1];
    float w0 = W1[c], w1 = W1[16 + c], w2 = W1[32 + c], w3 = W1[48 + c];
    u[t] = b1[c] + x0 * (w0 - w2) + x1 * (w1 - w3);
    v[t] = __float2half(x0 * w2 + x1 * w3);
    if (blockIdx.x == 0 && t < 16) v[NN * 16 + t] = __float2half(-60000.0f);
}

// layers 2/3: F=32 input features
__global__ __launch_bounds__(256) void k_pre32(const float* __restrict__ h, const float* __restrict__ W1,
                                               const float* __restrict__ b1, float* __restrict__ u,
                                               __half* __restrict__ v) {
    __shared__ float sh[16][33];
    __shared__ float wd[32][16];
    __shared__ float wv[32][16];
    int t = threadIdx.x;
    for (int i = t; i < 512; i += 256) {
        int f = i >> 4, c = i & 15;
        float wt = W1[i];            // rows 0..31 (x_i part)
        float wb = W1[512 + i];      // rows 32..63 (x_j - x_i part)
        wd[f][c] = wt - wb;
        wv[f][c] = wb;
    }
    int nb = blockIdx.x * 16;
    for (int i = t; i < 512; i += 256) sh[i >> 5][i & 31] = h[nb * 32 + i];
    __syncthreads();
    int c = t & 15, nl = t >> 4;
    float uu = b1[c], vv = 0.f;
#pragma unroll
    for (int f = 0; f < 32; ++f) {
        float hv = sh[nl][f];
        uu += hv * wd[f][c];
        vv += hv * wv[f][c];
    }
    int n = nb + nl;
    u[n * 16 + c] = uu;
    v[n * 16 + c] = __float2half(vv);
    if (blockIdx.x == 0 && t < 16) v[NN * 16 + t] = __float2half(-60000.0f);
}

// ---------------- CSR gather (register acc, 8-wide MLP) + @W2 ----------------
__global__ __launch_bounds__(256) void k_gather(const float* __restrict__ u, const __half* __restrict__ v,
                                                const int* __restrict__ ssrc, const int* __restrict__ offs,
                                                const int* __restrict__ offe,
                                                const float* __restrict__ W2, const float* __restrict__ b2,
                                                float* __restrict__ y) {
    __shared__ float sw2[16][32];
    __shared__ float sagg[16][17];
    int t = threadIdx.x;
    for (int i = t; i < 512; i += 256) sw2[i >> 5][i & 31] = W2[i];
    int c = t & 15, nl = t >> 4;
    int n = blockIdx.x * 16 + nl;
    int s0 = offs[n], e0 = offe[n];
    float uc = u[n * 16 + c];
    float acc = 0.f;
    for (int p = s0; p < e0; p += 8) {
        int idx[8];
#pragma unroll
        for (int i = 0; i < 8; ++i) idx[i] = (p + i < e0) ? ssrc[p + i] : NN;
        float vv[8];
#pragma unroll
        for (int i = 0; i < 8; ++i) vv[i] = __half2float(v[(size_t)idx[i] * 16 + c]);
#pragma unroll
        for (int i = 0; i < 8; ++i) acc += fmaxf(uc + vv[i], 0.f);
    }
    sagg[nl][c] = acc;
    __syncthreads();
    float cnt = (float)(e0 - s0);
    float y0 = b2[c] * cnt, y1 = b2[c + 16] * cnt;
#pragma unroll
    for (int k = 0; k < 16; ++k) {
        float a = sagg[nl][k];
        y0 += a * sw2[k][c];
        y1 += a * sw2[k][c + 16];
    }
    y[n * 32 + c] = y0;
    y[n * 32 + 16 + c] = y1;
}

// ---------------- BN stats straight from y: 256 blocks x 512 rows ----------------
__global__ __launch_bounds__(256) void k_bnstat2(const float* __restrict__ y, float* __restrict__ bns) {
    __shared__ float ssm[8][33];
    __shared__ float ssq[8][33];
    int t = threadIdx.x;
    int c = t & 31, g = t >> 5;             // 8 row-groups
    size_t r0 = (size_t)blockIdx.x * 512;
    float sm = 0.f, sq = 0.f;
    for (int i = 0; i < 64; ++i) {
        float val = y[(r0 + g + (size_t)i * 8) * 32 + c];
        sm += val;
        sq += val * val;
    }
    ssm[g][c] = sm;
    ssq[g][c] = sq;
    __syncthreads();
    if (t < 32) {
        float a = 0.f, bq = 0.f;
#pragma unroll
        for (int gg = 0; gg < 8; ++gg) { a += ssm[gg][t]; bq += ssq[gg][t]; }
        atomicAdd(&bns[t], a);
        atomicAdd(&bns[32 + t], bq);
    }
}

// ---------------- BN (training-mode batch stats) + ReLU ----------------
__global__ __launch_bounds__(256) void k_bnrelu(const float* __restrict__ y, const float* __restrict__ bns,
                                                const float* __restrict__ g, const float* __restrict__ bb,
                                                float* __restrict__ h) {
    int t = blockIdx.x * 256 + threadIdx.x;
    int j = t & 31;
    const float inv_n = 1.0f / (float)NN;
    float mean = bns[j] * inv_n;
    float var = bns[32 + j] * inv_n - mean * mean;
    float sc = g[j] * rsqrtf(var + EPS);
    float sh = bb[j] - mean * sc;
    h[t] = fmaxf(y[t] * sc + sh, 0.f);
}

// ---------------- fold dueling head into one GEMM: Bq/biasq prep ----------------
// q[b,n,a] = X1[b]·(vW + 0.5*(aW[n,:,a]-aW[n,:,1-a])) + vb + 0.5*(ab[n,a]-ab[n,1-a])
__global__ __launch_bounds__(256) void k_qprep(const float* __restrict__ vW, const float* __restrict__ vb,
                                               const float* __restrict__ aW, const float* __restrict__ ab,
                                               float* __restrict__ Bq, float* __restrict__ biasq) {
    int i = blockIdx.x * 256 + threadIdx.x;     // 16384
    int f = i >> 6, j = i & 63;
    int n = j >> 1, a = j & 1;
    float wa = aW[n * 512 + f * 2 + a];
    float wo = aW[n * 512 + f * 2 + (1 - a)];
    Bq[f * 64 + j] = vW[f] + 0.5f * (wa - wo);
    if (i < 64) biasq[i] = vb[0] + 0.5f * (ab[i] - ab[i ^ 1]);
}

// ---------------- fp32 tiled GEMM: C = [relu](A[M,K]@B[K,N] + bias) ----------------
#define GBM 64
#define GBN 64
#define GBK 16
__global__ __launch_bounds__(256) void k_gemm(const float* __restrict__ A, const float* __restrict__ Bm,
                                              const float* __restrict__ bias, float* __restrict__ C,
                                              int M, int Nc, int K, int relu) {
    __shared__ float As[GBK][GBM + 4];
    __shared__ float Bs[GBK][GBN + 4];
    int tid = threadIdx.x;
    int tx = tid & 15;
    int ty = tid >> 4;
    int rowBase = blockIdx.x * GBM;
    int colBase = blockIdx.y * GBN;
    int lr = tid >> 2;
    int lk = (tid & 3) * 4;
    int bkr = tid >> 4;
    int bc = (tid & 15) * 4;
    float acc[4][4] = {};
    for (int kt = 0; kt < K; kt += GBK) {
        float4 av = *(const float4*)(A + (size_t)(rowBase + lr) * K + kt + lk);
        As[lk + 0][lr] = av.x;
        As[lk + 1][lr] = av.y;
        As[lk + 2][lr] = av.z;
        As[lk + 3][lr] = av.w;
        float4 bv = *(const float4*)(Bm + (size_t)(kt + bkr) * Nc + colBase + bc);
        *(float4*)&Bs[bkr][bc] = bv;
        __syncthreads();
#pragma unroll
        for (int k = 0; k < GBK; ++k) {
            float4 ar = *(const float4*)&As[k][ty * 4];
            float4 br = *(const float4*)&Bs[k][tx * 4];
            acc[0][0] += ar.x * br.x; acc[0][1] += ar.x * br.y; acc[0][2] += ar.x * br.z; acc[0][3] += ar.x * br.w;
            acc[1][0] += ar.y * br.x; acc[1][1] += ar.y * br.y; acc[1][2] += ar.y * br.z; acc[1][3] += ar.y * br.w;
            acc[2][0] += ar.z * br.x; acc[2][1] += ar.z * br.y; acc[2][2] += ar.z * br.z; acc[2][3] += ar.z * br.w;
            acc[3][0] += ar.w * br.x; acc[3][1] += ar.w * br.y; acc[3][2] += ar.w * br.z; acc[3][3] += ar.w * br.w;
        }
        __syncthreads();
    }
    float b0 = bias[colBase + tx * 4 + 0];
    float b1 = bias[colBase + tx * 4 + 1];
    float b2 = bias[colBase + tx * 4 + 2];
    float b3 = bias[colBase + tx * 4 + 3];
#pragma unroll
    for (int i = 0; i < 4; ++i) {
        int row = rowBase + ty * 4 + i;
        float4 o;
        o.x = acc[i][0] + b0;
        o.y = acc[i][1] + b1;
        o.z = acc[i][2] + b2;
        o.w = acc[i][3] + b3;
        if (relu) {
            o.x = fmaxf(o.x, 0.f); o.y = fmaxf(o.y, 0.f);
            o.z = fmaxf(o.z, 0.f); o.w = fmaxf(o.w, 0.f);
        }
        *(float4*)(C + (size_t)row * Nc + colBase + tx * 4) = o;
    }
}

extern "C" void kernel_launch(void* const* d_in, const int* in_sizes, int n_in,
                              void* d_out, int out_size, void* d_ws, size_t ws_size,
                              hipStream_t stream) {
    const float* x    = (const float*)d_in[0];
    const int*   ei   = (const int*)d_in[1];
    const float* c1W1 = (const float*)d_in[2];
    const float* c1b1 = (const float*)d_in[3];
    const float* c1W2 = (const float*)d_in[4];
    const float* c1b2 = (const float*)d_in[5];
    const float* c2W1 = (const float*)d_in[6];
    const float* c2b1 = (const float*)d_in[7];
    const float* c2W2 = (const float*)d_in[8];
    const float* c2b2 = (const float*)d_in[9];
    const float* c3W1 = (const float*)d_in[10];
    const float* c3b1 = (const float*)d_in[11];
    const float* c3W2 = (const float*)d_in[12];
    const float* c3b2 = (const float*)d_in[13];
    const float* bn_g = (const float*)d_in[14];
    const float* bn_b = (const float*)d_in[15];
    const float* mW1  = (const float*)d_in[16];
    const float* mb1  = (const float*)d_in[17];
    const float* mW2  = (const float*)d_in[18];
    const float* mb2  = (const float*)d_in[19];
    const float* mW3  = (const float*)d_in[20];
    const float* mb3  = (const float*)d_in[21];
    const float* vW   = (const float*)d_in[22];
    const float* vb   = (const float*)d_in[23];
    const float* aW   = (const float*)d_in[24];
    const float* ab   = (const float*)d_in[25];
    float* out = (float*)d_out;

    char* p = (char*)d_ws;
    auto take = [&](size_t bytes) {
        char* r = p;
        p += (bytes + 255) & ~(size_t)255;
        return r;
    };
    int*    gcount = (int*)take((size_t)BKT * 4);
    int*    words  = (int*)take((size_t)BKT * CAP * 4);          // ~10 MB bucketed edges
    int*    ssrc   = (int*)take((size_t)BKT * CAP * 4);          // ~10 MB CSR-ordered srcs
    int*    offs   = (int*)take((size_t)NN * 4);
    int*    offe   = (int*)take((size_t)NN * 4);
    float*  u      = (float*)take((size_t)NN * HH * 4);
    __half* v      = (__half*)take((size_t)(NN + 1) * HH * 2);   // 4 MB (= one XCD L2) + dummy row
    float*  y      = (float*)take((size_t)NN * SS * 4);
    float*  h      = (float*)take((size_t)NN * SS * 4);
    float*  bns    = (float*)take(3 * 64 * 4);
    float*  Bq     = (float*)take(256 * 64 * 4);
    float*  biasq  = (float*)take(64 * 4);
    // X1/X2 reuse the y buffer (dead after last bn_relu): 4096*256*4 = 4 MB each
    float* X1 = y;
    float* X2 = y + (size_t)BB * 256;

    (void)hipMemsetAsync(gcount, 0, (size_t)BKT * 4, stream);
    (void)hipMemsetAsync(bns, 0, 3 * 64 * 4, stream);

    // CSR build: coarse bucket partition, then within-bucket sort (reused by all 3 layers)
    k_bsort<<<256, 256, 0, stream>>>(ei, gcount, words);
    k_csr<<<BKT, 256, 0, stream>>>(words, gcount, ssrc, offs, offe);
    // head-weight fold (independent of graph path; cheap)
    k_qprep<<<64, 256, 0, stream>>>(vW, vb, aW, ab, Bq, biasq);

    // layer 1
    k_pre1<<<NN * 16 / 256, 256, 0, stream>>>(x, c1W1, c1b1, u, v);
    k_gather<<<NN / 16, 256, 0, stream>>>(u, v, ssrc, offs, offe, c1W2, c1b2, y);
    k_bnstat2<<<256, 256, 0, stream>>>(y, bns);
    k_bnrelu<<<NN * 32 / 256, 256, 0, stream>>>(y, bns, bn_g, bn_b, h);
    // layer 2
    k_pre32<<<NN / 16, 256, 0, stream>>>(h, c2W1, c2b1, u, v);
    k_gather<<<NN / 16, 256, 0, stream>>>(u, v, ssrc, offs, offe, c2W2, c2b2, y);
    k_bnstat2<<<256, 256, 0, stream>>>(y, bns + 64);
    k_bnrelu<<<NN * 32 / 256, 256, 0, stream>>>(y, bns + 64, bn_g + 32, bn_b + 32, h);
    // layer 3
    k_pre32<<<NN / 16, 256, 0, stream>>>(h, c3W1, c3b1, u, v);
    k_gather<<<NN / 16, 256, 0, stream>>>(u, v, ssrc, offs, offe, c3W2, c3b2, y);
    k_bnstat2<<<256, 256, 0, stream>>>(y, bns + 128);
    k_bnrelu<<<NN * 32 / 256, 256, 0, stream>>>(y, bns + 128, bn_g + 64, bn_b + 64, h);

    // dense head MLP (h is [4096,1024] row-major by construction)
    k_gemm<<<dim3(BB / GBM, 256 / GBN), 256, 0, stream>>>(h, mW1, mb1, X1, BB, 256, 1024, 1);
    k_gemm<<<dim3(BB / GBM, 256 / GBN), 256, 0, stream>>>(X1, mW2, mb2, X2, BB, 256, 256, 1);
    k_gemm<<<dim3(BB / GBM, 256 / GBN), 256, 0, stream>>>(X2, mW3, mb3, X1, BB, 256, 256, 1);

    // dueling heads as one GEMM: out = X1 @ Bq + biasq   ([4096,256]@[256,64])
    k_gemm<<<dim3(BB / GBM, 1), 256, 0, stream>>>(X1, Bq, biasq, out, BB, 64, 256, 0);
}

// Round 9
// 428.660 us; speedup vs baseline: 2.3622x; 1.1656x over previous
//
#include <hip/hip_runtime.h>
#include <hip/hip_fp16.h>

#define NN 131072        // nodes
#define EE 2097152       // edges
#define SS 32            // channels
#define HH 16            // hidden
#define BB 4096          // graphs
#define EPS 1e-5f

#define BKT 512          // buckets (dst >> 8)
#define BNODES 256       // nodes per bucket
#define CAP 4864         // bucket capacity (avg 4096, +12 sigma)

typedef _Float16 f16x8 __attribute__((ext_vector_type(8)));
typedef float f32x4 __attribute__((ext_vector_type(4)));

// ---------------- coarse bucket partition of edges by dst>>8 ----------------
__global__ __launch_bounds__(256) void k_bsort(const int* __restrict__ ei, int* __restrict__ gcount,
                                               int* __restrict__ words) {
    __shared__ int hist[BKT];
    __shared__ int base[BKT];
    int t = threadIdx.x;
    for (int i = t; i < BKT; i += 256) hist[i] = 0;
    __syncthreads();
    int e0 = blockIdx.x * 8192;
    for (int it = 0; it < 32; ++it) {
        int dst = ei[EE + e0 + it * 256 + t];
        atomicAdd(&hist[dst >> 8], 1);
    }
    __syncthreads();
    for (int i = t; i < BKT; i += 256) {
        base[i] = atomicAdd(&gcount[i], hist[i]);
        hist[i] = 0;                    // reuse as intra-tile cursor
    }
    __syncthreads();
    for (int it = 0; it < 32; ++it) {
        int e = e0 + it * 256 + t;
        int src = ei[e];
        int dst = ei[EE + e];
        int b = dst >> 8;
        int r = atomicAdd(&hist[b], 1);
        words[(size_t)b * CAP + base[b] + r] = src | ((dst & 255) << 17);
    }
}

// ---------------- within-bucket sort to exact CSR (one block per bucket) ----------------
__global__ __launch_bounds__(256) void k_csr(const int* __restrict__ words, const int* __restrict__ gcount,
                                             int* __restrict__ ssrc, int* __restrict__ offs,
                                             int* __restrict__ offe) {
    __shared__ int hist[BNODES];
    __shared__ int sc[BNODES];
    __shared__ int base[BNODES];
    int t = threadIdx.x;
    int b = blockIdx.x;
    hist[t] = 0;
    __syncthreads();
    int cnt = gcount[b];
    const int* wp = words + (size_t)b * CAP;
    for (int p = t; p < cnt; p += 256) atomicAdd(&hist[wp[p] >> 17], 1);
    __syncthreads();
    int val = hist[t];
    sc[t] = val;
    __syncthreads();
    for (int d = 1; d < 256; d <<= 1) {
        int v2 = (t >= d) ? sc[t - d] : 0;
        __syncthreads();
        sc[t] += v2;
        __syncthreads();
    }
    base[t] = sc[t] - val;              // exclusive scan
    int gbase = b * CAP;
    offs[b * BNODES + t] = gbase + base[t];
    offe[b * BNODES + t] = gbase + sc[t];
    __syncthreads();
    hist[t] = 0;                        // reuse as per-node cursor
    __syncthreads();
    for (int p = t; p < cnt; p += 256) {
        int w = wp[p];
        int dl = w >> 17;
        int r = atomicAdd(&hist[dl], 1);
        ssrc[gbase + base[dl] + r] = w & 0x1FFFF;
    }
}

// ---------------- per-node pre-transform (u = x@(Wt-Wb)+b1 fp32, v = x@Wb fp16) ------------
__global__ __launch_bounds__(256) void k_pre1(const float* __restrict__ x, const float* __restrict__ W1,
                                              const float* __restrict__ b1, float* __restrict__ u,
                                              __half* __restrict__ v) {
    int t = blockIdx.x * 256 + threadIdx.x;     // N*16 threads
    int n = t >> 4, c = t & 15;
    float x0 = x[n * 2], x1 = x[n * 2 + 1];
    float w0 = W1[c], w1 = W1[16 + c], w2 = W1[32 + c], w3 = W1[48 + c];
    u[t] = b1[c] + x0 * (w0 - w2) + x1 * (w1 - w3);
    v[t] = __float2half(x0 * w2 + x1 * w3);
    if (blockIdx.x == 0 && t < 16) v[NN * 16 + t] = __float2half(-60000.0f);
}

// layers 2/3: F=32 input features
__global__ __launch_bounds__(256) void k_pre32(const float* __restrict__ h, const float* __restrict__ W1,
                                               const float* __restrict__ b1, float* __restrict__ u,
                                               __half* __restrict__ v) {
    __shared__ float sh[16][33];
    __shared__ float wd[32][16];
    __shared__ float wv[32][16];
    int t = threadIdx.x;
    for (int i = t; i < 512; i += 256) {
        int f = i >> 4, c = i & 15;
        float wt = W1[i];            // rows 0..31 (x_i part)
        float wb = W1[512 + i];      // rows 32..63 (x_j - x_i part)
        wd[f][c] = wt - wb;
        wv[f][c] = wb;
    }
    int nb = blockIdx.x * 16;
    for (int i = t; i < 512; i += 256) sh[i >> 5][i & 31] = h[nb * 32 + i];
    __syncthreads();
    int c = t & 15, nl = t >> 4;
    float uu = b1[c], vv = 0.f;
#pragma unroll
    for (int f = 0; f < 32; ++f) {
        float hv = sh[nl][f];
        uu += hv * wd[f][c];
        vv += hv * wv[f][c];
    }
    int n = nb + nl;
    u[n * 16 + c] = uu;
    v[n * 16 + c] = __float2half(vv);
    if (blockIdx.x == 0 && t < 16) v[NN * 16 + t] = __float2half(-60000.0f);
}

// ---------------- CSR gather (register acc, 8-wide MLP) + @W2 ----------------
__global__ __launch_bounds__(256) void k_gather(const float* __restrict__ u, const __half* __restrict__ v,
                                                const int* __restrict__ ssrc, const int* __restrict__ offs,
                                                const int* __restrict__ offe,
                                                const float* __restrict__ W2, const float* __restrict__ b2,
                                                float* __restrict__ y) {
    __shared__ float sw2[16][32];
    __shared__ float sagg[16][17];
    int t = threadIdx.x;
    for (int i = t; i < 512; i += 256) sw2[i >> 5][i & 31] = W2[i];
    int c = t & 15, nl = t >> 4;
    int n = blockIdx.x * 16 + nl;
    int s0 = offs[n], e0 = offe[n];
    float uc = u[n * 16 + c];
    float acc = 0.f;
    for (int p = s0; p < e0; p += 8) {
        int idx[8];
#pragma unroll
        for (int i = 0; i < 8; ++i) idx[i] = (p + i < e0) ? ssrc[p + i] : NN;
        float vv[8];
#pragma unroll
        for (int i = 0; i < 8; ++i) vv[i] = __half2float(v[(size_t)idx[i] * 16 + c]);
#pragma unroll
        for (int i = 0; i < 8; ++i) acc += fmaxf(uc + vv[i], 0.f);
    }
    sagg[nl][c] = acc;
    __syncthreads();
    float cnt = (float)(e0 - s0);
    float y0 = b2[c] * cnt, y1 = b2[c + 16] * cnt;
#pragma unroll
    for (int k = 0; k < 16; ++k) {
        float a = sagg[nl][k];
        y0 += a * sw2[k][c];
        y1 += a * sw2[k][c + 16];
    }
    y[n * 32 + c] = y0;
    y[n * 32 + 16 + c] = y1;
}

// ---------------- BN stats straight from y: 256 blocks x 512 rows ----------------
__global__ __launch_bounds__(256) void k_bnstat2(const float* __restrict__ y, float* __restrict__ bns) {
    __shared__ float ssm[8][33];
    __shared__ float ssq[8][33];
    int t = threadIdx.x;
    int c = t & 31, g = t >> 5;             // 8 row-groups
    size_t r0 = (size_t)blockIdx.x * 512;
    float sm = 0.f, sq = 0.f;
    for (int i = 0; i < 64; ++i) {
        float val = y[(r0 + g + (size_t)i * 8) * 32 + c];
        sm += val;
        sq += val * val;
    }
    ssm[g][c] = sm;
    ssq[g][c] = sq;
    __syncthreads();
    if (t < 32) {
        float a = 0.f, bq = 0.f;
#pragma unroll
        for (int gg = 0; gg < 8; ++gg) { a += ssm[gg][t]; bq += ssq[gg][t]; }
        atomicAdd(&bns[t], a);
        atomicAdd(&bns[32 + t], bq);
    }
}

// ---------------- BN (training-mode batch stats) + ReLU; optional fp16 mirror ----------------
__global__ __launch_bounds__(256) void k_bnrelu(const float* __restrict__ y, const float* __restrict__ bns,
                                                const float* __restrict__ g, const float* __restrict__ bb,
                                                float* __restrict__ h, _Float16* __restrict__ h16,
                                                int w16) {
    int t = blockIdx.x * 256 + threadIdx.x;
    int j = t & 31;
    const float inv_n = 1.0f / (float)NN;
    float mean = bns[j] * inv_n;
    float var = bns[32 + j] * inv_n - mean * mean;
    float sc = g[j] * rsqrtf(var + EPS);
    float sh = bb[j] - mean * sc;
    float val = fmaxf(y[t] * sc + sh, 0.f);
    h[t] = val;
    if (w16) h16[t] = (_Float16)val;
}

// ---------------- weight transpose fp32[K][N] -> fp16 [N][K] (N = pow2) ----------------
__global__ __launch_bounds__(256) void k_wtr(const float* __restrict__ W, _Float16* __restrict__ WT,
                                             int K, int nshift) {
    int i = blockIdx.x * 256 + threadIdx.x;
    int k = i >> nshift, n = i & ((1 << nshift) - 1);
    WT[(size_t)n * K + k] = (_Float16)W[i];
}

// ---------------- fold dueling head into one GEMM: BqT fp16 [64][256] + biasq ----------------
__global__ __launch_bounds__(256) void k_qprep(const float* __restrict__ vW, const float* __restrict__ vb,
                                               const float* __restrict__ aW, const float* __restrict__ ab,
                                               _Float16* __restrict__ BqT, float* __restrict__ biasq) {
    int i = blockIdx.x * 256 + threadIdx.x;     // 16384
    int f = i >> 6, j = i & 63;
    int n = j >> 1, a = j & 1;
    float wa = aW[n * 512 + f * 2 + a];
    float wo = aW[n * 512 + f * 2 + (1 - a)];
    BqT[(size_t)j * 256 + f] = (_Float16)(vW[f] + 0.5f * (wa - wo));
    if (i < 64) biasq[i] = vb[0] + 0.5f * (ab[i] - ab[i ^ 1]);
}

// ---------------- MFMA fp16 GEMM: C = [relu](A[M,K] @ BT[N,K]^T + bias) ----------------
// 16x16x32 f16 MFMA; A/B frag: idx=lane&15, k=quad*8+j (16 B/lane loads, no LDS);
// C/D: col=lane&15, row=quad*4+reg. Wave = 64 rows x 16 cols; block = 64x64 tile.
__global__ __launch_bounds__(256) void k_mgemm(const _Float16* __restrict__ A, const _Float16* __restrict__ BT,
                                               const float* __restrict__ bias, float* __restrict__ Cf,
                                               _Float16* __restrict__ Ch, int M, int N, int K,
                                               int relu, int out16) {
    int tid = threadIdx.x;
    int w = tid >> 6, l = tid & 63, q = l >> 4, r = l & 15;
    int rowBase = blockIdx.x * 64;
    int col = blockIdx.y * 64 + w * 16 + r;
    const _Float16* ap = A + (size_t)(rowBase + r) * K + q * 8;
    const _Float16* bp = BT + (size_t)col * K + q * 8;
    f32x4 z = {0.f, 0.f, 0.f, 0.f};
    f32x4 acc[4] = {z, z, z, z};
    for (int k0 = 0; k0 < K; k0 += 32) {
        f16x8 bf = *(const f16x8*)(bp + k0);
        f16x8 a0 = *(const f16x8*)(ap + k0);
        f16x8 a1 = *(const f16x8*)(ap + k0 + (size_t)16 * K);
        f16x8 a2 = *(const f16x8*)(ap + k0 + (size_t)32 * K);
        f16x8 a3 = *(const f16x8*)(ap + k0 + (size_t)48 * K);
        acc[0] = __builtin_amdgcn_mfma_f32_16x16x32_f16(a0, bf, acc[0], 0, 0, 0);
        acc[1] = __builtin_amdgcn_mfma_f32_16x16x32_f16(a1, bf, acc[1], 0, 0, 0);
        acc[2] = __builtin_amdgcn_mfma_f32_16x16x32_f16(a2, bf, acc[2], 0, 0, 0);
        acc[3] = __builtin_amdgcn_mfma_f32_16x16x32_f16(a3, bf, acc[3], 0, 0, 0);
    }
    float bv = bias[col];
#pragma unroll
    for (int rt = 0; rt < 4; ++rt) {
#pragma unroll
        for (int i = 0; i < 4; ++i) {
            int row = rowBase + rt * 16 + q * 4 + i;
            float val = acc[rt][i] + bv;
            if (relu) val = fmaxf(val, 0.f);
            if (out16) Ch[(size_t)row * N + col] = (_Float16)val;
            else       Cf[(size_t)row * N + col] = val;
        }
    }
}

extern "C" void kernel_launch(void* const* d_in, const int* in_sizes, int n_in,
                              void* d_out, int out_size, void* d_ws, size_t ws_size,
                              hipStream_t stream) {
    const float* x    = (const float*)d_in[0];
    const int*   ei   = (const int*)d_in[1];
    const float* c1W1 = (const float*)d_in[2];
    const float* c1b1 = (const float*)d_in[3];
    const float* c1W2 = (const float*)d_in[4];
    const float* c1b2 = (const float*)d_in[5];
    const float* c2W1 = (const float*)d_in[6];
    const float* c2b1 = (const float*)d_in[7];
    const float* c2W2 = (const float*)d_in[8];
    const float* c2b2 = (const float*)d_in[9];
    const float* c3W1 = (const float*)d_in[10];
    const float* c3b1 = (const float*)d_in[11];
    const float* c3W2 = (const float*)d_in[12];
    const float* c3b2 = (const float*)d_in[13];
    const float* bn_g = (const float*)d_in[14];
    const float* bn_b = (const float*)d_in[15];
    const float* mW1  = (const float*)d_in[16];
    const float* mb1  = (const float*)d_in[17];
    const float* mW2  = (const float*)d_in[18];
    const float* mb2  = (const float*)d_in[19];
    const float* mW3  = (const float*)d_in[20];
    const float* mb3  = (const float*)d_in[21];
    const float* vW   = (const float*)d_in[22];
    const float* vb   = (const float*)d_in[23];
    const float* aW   = (const float*)d_in[24];
    const float* ab   = (const float*)d_in[25];
    float* out = (float*)d_out;

    char* p = (char*)d_ws;
    auto take = [&](size_t bytes) {
        char* r = p;
        p += (bytes + 255) & ~(size_t)255;
        return r;
    };
    int*       gcount = (int*)take((size_t)BKT * 4);
    int*       words  = (int*)take((size_t)BKT * CAP * 4);        // ~10 MB bucketed edges
    int*       ssrc   = (int*)take((size_t)BKT * CAP * 4);        // ~10 MB CSR-ordered srcs
    int*       offs   = (int*)take((size_t)NN * 4);
    int*       offe   = (int*)take((size_t)NN * 4);
    float*     u      = (float*)take((size_t)NN * HH * 4);
    __half*    v      = (__half*)take((size_t)(NN + 1) * HH * 2); // 4 MB (= one XCD L2) + dummy row
    float*     y      = (float*)take((size_t)NN * SS * 4);
    float*     h      = (float*)take((size_t)NN * SS * 4);
    _Float16*  h16    = (_Float16*)take((size_t)NN * SS * 2);     // fp16 mirror for MFMA GEMM
    float*     bns    = (float*)take(3 * 64 * 4);
    _Float16*  W1T    = (_Float16*)take((size_t)256 * 1024 * 2);
    _Float16*  W2T    = (_Float16*)take((size_t)256 * 256 * 2);
    _Float16*  W3T    = (_Float16*)take((size_t)256 * 256 * 2);
    _Float16*  BqT    = (_Float16*)take((size_t)64 * 256 * 2);
    float*     biasq  = (float*)take(64 * 4);
    _Float16*  Xa     = (_Float16*)take((size_t)BB * 256 * 2);
    _Float16*  Xb     = (_Float16*)take((size_t)BB * 256 * 2);

    (void)hipMemsetAsync(gcount, 0, (size_t)BKT * 4, stream);
    (void)hipMemsetAsync(bns, 0, 3 * 64 * 4, stream);

    // CSR build: coarse bucket partition, then within-bucket sort (reused by all 3 layers)
    k_bsort<<<256, 256, 0, stream>>>(ei, gcount, words);
    k_csr<<<BKT, 256, 0, stream>>>(words, gcount, ssrc, offs, offe);
    // head weight prep (independent of graph path; cheap)
    k_wtr<<<1024, 256, 0, stream>>>(mW1, W1T, 1024, 8);
    k_wtr<<<256, 256, 0, stream>>>(mW2, W2T, 256, 8);
    k_wtr<<<256, 256, 0, stream>>>(mW3, W3T, 256, 8);
    k_qprep<<<64, 256, 0, stream>>>(vW, vb, aW, ab, BqT, biasq);

    // layer 1
    k_pre1<<<NN * 16 / 256, 256, 0, stream>>>(x, c1W1, c1b1, u, v);
    k_gather<<<NN / 16, 256, 0, stream>>>(u, v, ssrc, offs, offe, c1W2, c1b2, y);
    k_bnstat2<<<256, 256, 0, stream>>>(y, bns);
    k_bnrelu<<<NN * 32 / 256, 256, 0, stream>>>(y, bns, bn_g, bn_b, h, h16, 0);
    // layer 2
    k_pre32<<<NN / 16, 256, 0, stream>>>(h, c2W1, c2b1, u, v);
    k_gather<<<NN / 16, 256, 0, stream>>>(u, v, ssrc, offs, offe, c2W2, c2b2, y);
    k_bnstat2<<<256, 256, 0, stream>>>(y, bns + 64);
    k_bnrelu<<<NN * 32 / 256, 256, 0, stream>>>(y, bns + 64, bn_g + 32, bn_b + 32, h, h16, 0);
    // layer 3 (emit fp16 mirror: h16 is the [4096,1024] GEMM A-matrix)
    k_pre32<<<NN / 16, 256, 0, stream>>>(h, c3W1, c3b1, u, v);
    k_gather<<<NN / 16, 256, 0, stream>>>(u, v, ssrc, offs, offe, c3W2, c3b2, y);
    k_bnstat2<<<256, 256, 0, stream>>>(y, bns + 128);
    k_bnrelu<<<NN * 32 / 256, 256, 0, stream>>>(y, bns + 128, bn_g + 64, bn_b + 64, h, h16, 1);

    // dense head MLP on matrix cores (fp16 in, fp32 accumulate)
    k_mgemm<<<dim3(BB / 64, 4), 256, 0, stream>>>(h16, W1T, mb1, nullptr, Xa, BB, 256, 1024, 1, 1);
    k_mgemm<<<dim3(BB / 64, 4), 256, 0, stream>>>(Xa, W2T, mb2, nullptr, Xb, BB, 256, 256, 1, 1);
    k_mgemm<<<dim3(BB / 64, 4), 256, 0, stream>>>(Xb, W3T, mb3, nullptr, Xa, BB, 256, 256, 1, 1);
    // dueling heads folded into one GEMM: out = X @ BqT^T + biasq
    k_mgemm<<<dim3(BB / 64, 1), 256, 0, stream>>>(Xa, BqT, biasq, out, nullptr, BB, 64, 256, 0, 0);
}

// Round 10
// 375.317 us; speedup vs baseline: 2.6979x; 1.1421x over previous
//
#include <hip/hip_runtime.h>
#include <hip/hip_fp16.h>

#define NN 131072        // nodes
#define EE 2097152       // edges
#define SS 32            // channels
#define HH 16            // hidden
#define BB 4096          // graphs
#define EPS 1e-5f

#define BKT 512          // buckets (dst >> 8)
#define BNODES 256       // nodes per bucket
#define CAP 4864         // bucket capacity (avg 4096, +12 sigma)

typedef _Float16 f16x8 __attribute__((ext_vector_type(8)));
typedef float f32x4 __attribute__((ext_vector_type(4)));

// ---------------- coarse bucket partition of edges by dst>>8 ----------------
// 512 blocks x 4096 edges (R9: 256 blocks = 1/CU = 8.5% occupancy was latency-bound)
__global__ __launch_bounds__(256) void k_bsort(const int* __restrict__ ei, int* __restrict__ gcount,
                                               int* __restrict__ words) {
    __shared__ int hist[BKT];
    __shared__ int base[BKT];
    int t = threadIdx.x;
    for (int i = t; i < BKT; i += 256) hist[i] = 0;
    __syncthreads();
    int e0 = blockIdx.x * 4096;
    for (int it = 0; it < 16; ++it) {
        int dst = ei[EE + e0 + it * 256 + t];
        atomicAdd(&hist[dst >> 8], 1);
    }
    __syncthreads();
    for (int i = t; i < BKT; i += 256) {
        base[i] = atomicAdd(&gcount[i], hist[i]);
        hist[i] = 0;                    // reuse as intra-tile cursor
    }
    __syncthreads();
    for (int it = 0; it < 16; ++it) {
        int e = e0 + it * 256 + t;
        int src = ei[e];
        int dst = ei[EE + e];
        int b = dst >> 8;
        int r = atomicAdd(&hist[b], 1);
        words[(size_t)b * CAP + base[b] + r] = src | ((dst & 255) << 17);
    }
}

// ---------------- within-bucket sort to exact CSR (one block per bucket) ----------------
__global__ __launch_bounds__(256) void k_csr(const int* __restrict__ words, const int* __restrict__ gcount,
                                             int* __restrict__ ssrc, int* __restrict__ offs,
                                             int* __restrict__ offe) {
    __shared__ int hist[BNODES];
    __shared__ int sc[BNODES];
    __shared__ int base[BNODES];
    int t = threadIdx.x;
    int b = blockIdx.x;
    hist[t] = 0;
    __syncthreads();
    int cnt = gcount[b];
    const int* wp = words + (size_t)b * CAP;
    for (int p = t; p < cnt; p += 256) atomicAdd(&hist[wp[p] >> 17], 1);
    __syncthreads();
    int val = hist[t];
    sc[t] = val;
    __syncthreads();
    for (int d = 1; d < 256; d <<= 1) {
        int v2 = (t >= d) ? sc[t - d] : 0;
        __syncthreads();
        sc[t] += v2;
        __syncthreads();
    }
    base[t] = sc[t] - val;              // exclusive scan
    int gbase = b * CAP;
    offs[b * BNODES + t] = gbase + base[t];
    offe[b * BNODES + t] = gbase + sc[t];
    __syncthreads();
    hist[t] = 0;                        // reuse as per-node cursor
    __syncthreads();
    for (int p = t; p < cnt; p += 256) {
        int w = wp[p];
        int dl = w >> 17;
        int r = atomicAdd(&hist[dl], 1);
        ssrc[gbase + base[dl] + r] = w & 0x1FFFF;
    }
}

// ---------------- layer-1 pre-transform (u = x@(Wt-Wb)+b1 fp32, v = x@Wb fp16) ------------
__global__ __launch_bounds__(256) void k_pre1(const float* __restrict__ x, const float* __restrict__ W1,
                                              const float* __restrict__ b1, float* __restrict__ u,
                                              __half* __restrict__ v) {
    int t = blockIdx.x * 256 + threadIdx.x;     // N*16 threads
    int n = t >> 4, c = t & 15;
    float x0 = x[n * 2], x1 = x[n * 2 + 1];
    float w0 = W1[c], w1 = W1[16 + c], w2 = W1[32 + c], w3 = W1[48 + c];
    u[t] = b1[c] + x0 * (w0 - w2) + x1 * (w1 - w3);
    v[t] = __float2half(x0 * w2 + x1 * w3);
    if (blockIdx.x == 0 && t < 16) v[NN * 16 + t] = __float2half(-60000.0f);
}

// ---------------- fused BN+ReLU + pre-transform for layers 2/3 ----------------
// reads y (pre-BN conv output) + stats; emits u,v directly (no fp32 h round-trip)
__global__ __launch_bounds__(256) void k_bnpre(const float* __restrict__ y, const float* __restrict__ bns,
                                               const float* __restrict__ g, const float* __restrict__ bb,
                                               const float* __restrict__ W1, const float* __restrict__ b1,
                                               float* __restrict__ u, __half* __restrict__ v) {
    __shared__ float sh[16][33];
    __shared__ float wd[32][16];
    __shared__ float wv[32][16];
    __shared__ float scL[32], soL[32];
    int t = threadIdx.x;
    if (t < 32) {
        const float inv_n = 1.0f / (float)NN;
        float mean = bns[t] * inv_n;
        float var = bns[32 + t] * inv_n - mean * mean;
        float s = g[t] * rsqrtf(var + EPS);
        scL[t] = s;
        soL[t] = bb[t] - mean * s;
    }
    for (int i = t; i < 512; i += 256) {
        int f = i >> 4, c = i & 15;
        float wt = W1[i];            // rows 0..31 (x_i part)
        float wb = W1[512 + i];      // rows 32..63 (x_j - x_i part)
        wd[f][c] = wt - wb;
        wv[f][c] = wb;
    }
    __syncthreads();
    int nb = blockIdx.x * 16;
    for (int i = t; i < 512; i += 256) {
        int col = i & 31;
        sh[i >> 5][col] = fmaxf(y[nb * 32 + i] * scL[col] + soL[col], 0.f);
    }
    __syncthreads();
    int c = t & 15, nl = t >> 4;
    float uu = b1[c], vv = 0.f;
#pragma unroll
    for (int f = 0; f < 32; ++f) {
        float hv = sh[nl][f];
        uu += hv * wd[f][c];
        vv += hv * wv[f][c];
    }
    int n = nb + nl;
    u[n * 16 + c] = uu;
    v[n * 16 + c] = __float2half(vv);
    if (blockIdx.x == 0 && t < 16) v[NN * 16 + t] = __float2half(-60000.0f);
}

// ---------------- CSR gather: 8 lanes/node, half2 loads, deferred W2 stage ----------------
// 8 nodes/wave (2x R9), 16M 4B gather-loads (was 32M 2B), W2 global load overlaps gather.
__global__ __launch_bounds__(256) void k_gather(const float* __restrict__ u, const __half* __restrict__ v,
                                                const int* __restrict__ ssrc, const int* __restrict__ offs,
                                                const int* __restrict__ offe,
                                                const float* __restrict__ W2, const float* __restrict__ b2,
                                                float* __restrict__ y) {
    __shared__ float sw2[512];          // [k][32]
    __shared__ float sagg[32 * 18];     // stride 18: 8B-aligned pairs, 2-way conflicts only
    __shared__ float cntL[32];
    int t = threadIdx.x;
    float w2a = W2[t], w2b = W2[t + 256];         // stage in regs; LDS write after gather
    float b2r0 = b2[(t & 7) * 4], b2r1 = b2[(t & 7) * 4 + 1];
    float b2r2 = b2[(t & 7) * 4 + 2], b2r3 = b2[(t & 7) * 4 + 3];
    int nl = t >> 3, c2 = t & 7;
    int n = blockIdx.x * 32 + nl;
    int s0 = offs[n], e0 = offe[n];
    float2 uc = *(const float2*)(u + (size_t)n * 16 + 2 * c2);
    float a0 = 0.f, a1 = 0.f;
    for (int p = s0; p < e0; p += 8) {
        int idx[8];
#pragma unroll
        for (int i = 0; i < 8; ++i) idx[i] = (p + i < e0) ? ssrc[p + i] : NN;
        float2 vv[8];
#pragma unroll
        for (int i = 0; i < 8; ++i)
            vv[i] = __half22float2(*(const __half2*)(v + (size_t)idx[i] * 16 + 2 * c2));
#pragma unroll
        for (int i = 0; i < 8; ++i) {
            a0 += fmaxf(uc.x + vv[i].x, 0.f);
            a1 += fmaxf(uc.y + vv[i].y, 0.f);
        }
    }
    sagg[nl * 18 + 2 * c2] = a0;
    sagg[nl * 18 + 2 * c2 + 1] = a1;
    if (c2 == 0) cntL[nl] = (float)(e0 - s0);
    sw2[t] = w2a;
    sw2[t + 256] = w2b;
    __syncthreads();
    // epilogue: 8 threads/node, 4 output channels each
    int node = t >> 3, oc = (t & 7) * 4;
    float cw = cntL[node];
    float o0 = b2r0 * cw, o1 = b2r1 * cw, o2 = b2r2 * cw, o3 = b2r3 * cw;
#pragma unroll
    for (int k = 0; k < 16; ++k) {
        float a = sagg[node * 18 + k];
        o0 += a * sw2[k * 32 + oc];
        o1 += a * sw2[k * 32 + oc + 1];
        o2 += a * sw2[k * 32 + oc + 2];
        o3 += a * sw2[k * 32 + oc + 3];
    }
    *(float4*)(y + (size_t)(blockIdx.x * 32 + node) * 32 + oc) = make_float4(o0, o1, o2, o3);
}

// ---------------- BN stats straight from y: 256 blocks x 512 rows ----------------
__global__ __launch_bounds__(256) void k_bnstat2(const float* __restrict__ y, float* __restrict__ bns) {
    __shared__ float ssm[8][33];
    __shared__ float ssq[8][33];
    int t = threadIdx.x;
    int c = t & 31, g = t >> 5;             // 8 row-groups
    size_t r0 = (size_t)blockIdx.x * 512;
    float sm = 0.f, sq = 0.f;
    for (int i = 0; i < 64; ++i) {
        float val = y[(r0 + g + (size_t)i * 8) * 32 + c];
        sm += val;
        sq += val * val;
    }
    ssm[g][c] = sm;
    ssq[g][c] = sq;
    __syncthreads();
    if (t < 32) {
        float a = 0.f, bq = 0.f;
#pragma unroll
        for (int gg = 0; gg < 8; ++gg) { a += ssm[gg][t]; bq += ssq[gg][t]; }
        atomicAdd(&bns[t], a);
        atomicAdd(&bns[32 + t], bq);
    }
}

// ---------------- layer-3 BN+ReLU -> fp16 GEMM input only ----------------
__global__ __launch_bounds__(256) void k_bnrelu16(const float* __restrict__ y, const float* __restrict__ bns,
                                                  const float* __restrict__ g, const float* __restrict__ bb,
                                                  _Float16* __restrict__ h16) {
    int t = blockIdx.x * 256 + threadIdx.x;
    int j = t & 31;
    const float inv_n = 1.0f / (float)NN;
    float mean = bns[j] * inv_n;
    float var = bns[32 + j] * inv_n - mean * mean;
    float sc = g[j] * rsqrtf(var + EPS);
    float sh = bb[j] - mean * sc;
    h16[t] = (_Float16)fmaxf(y[t] * sc + sh, 0.f);
}

// ---------------- weight transpose fp32[K][N] -> fp16 [N][K] (N = pow2) ----------------
__global__ __launch_bounds__(256) void k_wtr(const float* __restrict__ W, _Float16* __restrict__ WT,
                                             int K, int nshift) {
    int i = blockIdx.x * 256 + threadIdx.x;
    int k = i >> nshift, n = i & ((1 << nshift) - 1);
    WT[(size_t)n * K + k] = (_Float16)W[i];
}

// ---------------- fold dueling head into one GEMM: BqT fp16 [64][256] + biasq ----------------
__global__ __launch_bounds__(256) void k_qprep(const float* __restrict__ vW, const float* __restrict__ vb,
                                               const float* __restrict__ aW, const float* __restrict__ ab,
                                               _Float16* __restrict__ BqT, float* __restrict__ biasq) {
    int i = blockIdx.x * 256 + threadIdx.x;     // 16384
    int f = i >> 6, j = i & 63;
    int n = j >> 1, a = j & 1;
    float wa = aW[n * 512 + f * 2 + a];
    float wo = aW[n * 512 + f * 2 + (1 - a)];
    BqT[(size_t)j * 256 + f] = (_Float16)(vW[f] + 0.5f * (wa - wo));
    if (i < 64) biasq[i] = vb[0] + 0.5f * (ab[i] - ab[i ^ 1]);
}

// ---------------- MFMA fp16 GEMM: C = [relu](A[M,K] @ BT[N,K]^T + bias) ----------------
__global__ __launch_bounds__(256) void k_mgemm(const _Float16* __restrict__ A, const _Float16* __restrict__ BT,
                                               const float* __restrict__ bias, float* __restrict__ Cf,
                                               _Float16* __restrict__ Ch, int M, int N, int K,
                                               int relu, int out16) {
    int tid = threadIdx.x;
    int w = tid >> 6, l = tid & 63, q = l >> 4, r = l & 15;
    int rowBase = blockIdx.x * 64;
    int col = blockIdx.y * 64 + w * 16 + r;
    const _Float16* ap = A + (size_t)(rowBase + r) * K + q * 8;
    const _Float16* bp = BT + (size_t)col * K + q * 8;
    f32x4 z = {0.f, 0.f, 0.f, 0.f};
    f32x4 acc[4] = {z, z, z, z};
    for (int k0 = 0; k0 < K; k0 += 32) {
        f16x8 bf = *(const f16x8*)(bp + k0);
        f16x8 a0 = *(const f16x8*)(ap + k0);
        f16x8 a1 = *(const f16x8*)(ap + k0 + (size_t)16 * K);
        f16x8 a2 = *(const f16x8*)(ap + k0 + (size_t)32 * K);
        f16x8 a3 = *(const f16x8*)(ap + k0 + (size_t)48 * K);
        acc[0] = __builtin_amdgcn_mfma_f32_16x16x32_f16(a0, bf, acc[0], 0, 0, 0);
        acc[1] = __builtin_amdgcn_mfma_f32_16x16x32_f16(a1, bf, acc[1], 0, 0, 0);
        acc[2] = __builtin_amdgcn_mfma_f32_16x16x32_f16(a2, bf, acc[2], 0, 0, 0);
        acc[3] = __builtin_amdgcn_mfma_f32_16x16x32_f16(a3, bf, acc[3], 0, 0, 0);
    }
    float bv = bias[col];
#pragma unroll
    for (int rt = 0; rt < 4; ++rt) {
#pragma unroll
        for (int i = 0; i < 4; ++i) {
            int row = rowBase + rt * 16 + q * 4 + i;
            float val = acc[rt][i] + bv;
            if (relu) val = fmaxf(val, 0.f);
            if (out16) Ch[(size_t)row * N + col] = (_Float16)val;
            else       Cf[(size_t)row * N + col] = val;
        }
    }
}

extern "C" void kernel_launch(void* const* d_in, const int* in_sizes, int n_in,
                              void* d_out, int out_size, void* d_ws, size_t ws_size,
                              hipStream_t stream) {
    const float* x    = (const float*)d_in[0];
    const int*   ei   = (const int*)d_in[1];
    const float* c1W1 = (const float*)d_in[2];
    const float* c1b1 = (const float*)d_in[3];
    const float* c1W2 = (const float*)d_in[4];
    const float* c1b2 = (const float*)d_in[5];
    const float* c2W1 = (const float*)d_in[6];
    const float* c2b1 = (const float*)d_in[7];
    const float* c2W2 = (const float*)d_in[8];
    const float* c2b2 = (const float*)d_in[9];
    const float* c3W1 = (const float*)d_in[10];
    const float* c3b1 = (const float*)d_in[11];
    const float* c3W2 = (const float*)d_in[12];
    const float* c3b2 = (const float*)d_in[13];
    const float* bn_g = (const float*)d_in[14];
    const float* bn_b = (const float*)d_in[15];
    const float* mW1  = (const float*)d_in[16];
    const float* mb1  = (const float*)d_in[17];
    const float* mW2  = (const float*)d_in[18];
    const float* mb2  = (const float*)d_in[19];
    const float* mW3  = (const float*)d_in[20];
    const float* mb3  = (const float*)d_in[21];
    const float* vW   = (const float*)d_in[22];
    const float* vb   = (const float*)d_in[23];
    const float* aW   = (const float*)d_in[24];
    const float* ab   = (const float*)d_in[25];
    float* out = (float*)d_out;

    char* p = (char*)d_ws;
    auto take = [&](size_t bytes) {
        char* r = p;
        p += (bytes + 255) & ~(size_t)255;
        return r;
    };
    int*       gcount = (int*)take((size_t)BKT * 4);
    int*       words  = (int*)take((size_t)BKT * CAP * 4);        // ~10 MB bucketed edges
    int*       ssrc   = (int*)take((size_t)BKT * CAP * 4);        // ~10 MB CSR-ordered srcs
    int*       offs   = (int*)take((size_t)NN * 4);
    int*       offe   = (int*)take((size_t)NN * 4);
    float*     u      = (float*)take((size_t)NN * HH * 4);
    __half*    v      = (__half*)take((size_t)(NN + 1) * HH * 2); // 4 MB (= one XCD L2) + dummy row
    float*     y      = (float*)take((size_t)NN * SS * 4);
    _Float16*  h16    = (_Float16*)take((size_t)NN * SS * 2);     // fp16 GEMM A-matrix
    float*     bns    = (float*)take(3 * 64 * 4);
    _Float16*  W1T    = (_Float16*)take((size_t)256 * 1024 * 2);
    _Float16*  W2T    = (_Float16*)take((size_t)256 * 256 * 2);
    _Float16*  W3T    = (_Float16*)take((size_t)256 * 256 * 2);
    _Float16*  BqT    = (_Float16*)take((size_t)64 * 256 * 2);
    float*     biasq  = (float*)take(64 * 4);
    _Float16*  Xa     = (_Float16*)take((size_t)BB * 256 * 2);
    _Float16*  Xb     = (_Float16*)take((size_t)BB * 256 * 2);

    (void)hipMemsetAsync(gcount, 0, (size_t)BKT * 4, stream);
    (void)hipMemsetAsync(bns, 0, 3 * 64 * 4, stream);

    // CSR build: coarse bucket partition, then within-bucket sort (reused by all 3 layers)
    k_bsort<<<512, 256, 0, stream>>>(ei, gcount, words);
    k_csr<<<BKT, 256, 0, stream>>>(words, gcount, ssrc, offs, offe);
    // head weight prep (independent of graph path; cheap)
    k_wtr<<<1024, 256, 0, stream>>>(mW1, W1T, 1024, 8);
    k_wtr<<<256, 256, 0, stream>>>(mW2, W2T, 256, 8);
    k_wtr<<<256, 256, 0, stream>>>(mW3, W3T, 256, 8);
    k_qprep<<<64, 256, 0, stream>>>(vW, vb, aW, ab, BqT, biasq);

    // layer 1
    k_pre1<<<NN * 16 / 256, 256, 0, stream>>>(x, c1W1, c1b1, u, v);
    k_gather<<<NN / 32, 256, 0, stream>>>(u, v, ssrc, offs, offe, c1W2, c1b2, y);
    k_bnstat2<<<256, 256, 0, stream>>>(y, bns);
    // layer 2 (fused BN+ReLU+pre)
    k_bnpre<<<NN / 16, 256, 0, stream>>>(y, bns, bn_g, bn_b, c2W1, c2b1, u, v);
    k_gather<<<NN / 32, 256, 0, stream>>>(u, v, ssrc, offs, offe, c2W2, c2b2, y);
    k_bnstat2<<<256, 256, 0, stream>>>(y, bns + 64);
    // layer 3 (fused BN+ReLU+pre)
    k_bnpre<<<NN / 16, 256, 0, stream>>>(y, bns + 64, bn_g + 32, bn_b + 32, c3W1, c3b1, u, v);
    k_gather<<<NN / 32, 256, 0, stream>>>(u, v, ssrc, offs, offe, c3W2, c3b2, y);
    k_bnstat2<<<256, 256, 0, stream>>>(y, bns + 128);
    k_bnrelu16<<<NN * 32 / 256, 256, 0, stream>>>(y, bns + 128, bn_g + 64, bn_b + 64, h16);

    // dense head MLP on matrix cores (fp16 in, fp32 accumulate)
    k_mgemm<<<dim3(BB / 64, 4), 256, 0, stream>>>(h16, W1T, mb1, nullptr, Xa, BB, 256, 1024, 1, 1);
    k_mgemm<<<dim3(BB / 64, 4), 256, 0, stream>>>(Xa, W2T, mb2, nullptr, Xb, BB, 256, 256, 1, 1);
    k_mgemm<<<dim3(BB / 64, 4), 256, 0, stream>>>(Xb, W3T, mb3, nullptr, Xa, BB, 256, 256, 1, 1);
    // dueling heads folded into one GEMM: out = X @ BqT^T + biasq
    k_mgemm<<<dim3(BB / 64, 1), 256, 0, stream>>>(Xa, BqT, biasq, out, nullptr, BB, 64, 256, 0, 0);
}

// Round 12
// 368.986 us; speedup vs baseline: 2.7442x; 1.0172x over previous
//
#include <hip/hip_runtime.h>
#include <hip/hip_fp16.h>

#define NN 131072        // nodes
#define EE 2097152       // edges
#define SS 32            // channels
#define HH 16            // hidden
#define BB 4096          // graphs
#define EPS 1e-5f

#define BKT 512          // buckets (dst >> 8)
#define BNODES 256       // nodes per bucket
#define CAP 4864         // bucket capacity (avg 4096, +12 sigma)
#define TILE 8192        // edges per bsort block

typedef _Float16 f16x8 __attribute__((ext_vector_type(8)));
typedef float f32x4 __attribute__((ext_vector_type(4)));

// ---------------- bucket partition, LDS-staged for line-coalesced writes ----------------
// Rank edges into LDS-sorted tile order, then copy out position-ordered: a wave's 64
// consecutive slots span ~4 buckets => ~4-8 full-line bursts (R10: direct scatter
// touched ~60 lines per wave-store => 45 us write-bound).
// R11 BUGFIX: gshift must include the b*CAP segment offset.
__global__ __launch_bounds__(256) void k_bsort(const int* __restrict__ ei, int* __restrict__ gcount,
                                               int* __restrict__ words) {
    __shared__ int cnt[BKT];
    __shared__ int tstart[BKT];
    __shared__ int gshift[BKT];
    __shared__ int stmp[256];
    __shared__ int sword[TILE];
    __shared__ int sdst[TILE];
    int t = threadIdx.x;
    cnt[t] = 0;
    cnt[t + 256] = 0;
    __syncthreads();
    int e0 = blockIdx.x * TILE;
#pragma unroll
    for (int it = 0; it < TILE / 256; ++it) {
        int dst = ei[EE + e0 + it * 256 + t];
        atomicAdd(&cnt[dst >> 8], 1);
    }
    __syncthreads();
    int c0 = cnt[2 * t], c1 = cnt[2 * t + 1];
    int tot = c0 + c1;
    stmp[t] = tot;
    __syncthreads();
    for (int d = 1; d < 256; d <<= 1) {
        int v = (t >= d) ? stmp[t - d] : 0;
        __syncthreads();
        stmp[t] += v;
        __syncthreads();
    }
    int excl = stmp[t] - tot;
    tstart[2 * t] = excl;
    tstart[2 * t + 1] = excl + c0;
    gshift[2 * t]     = (2 * t) * CAP     + atomicAdd(&gcount[2 * t], c0) - excl;
    gshift[2 * t + 1] = (2 * t + 1) * CAP + atomicAdd(&gcount[2 * t + 1], c1) - (excl + c0);
    cnt[2 * t] = 0;
    cnt[2 * t + 1] = 0;                 // reuse as intra-tile cursor
    __syncthreads();
#pragma unroll
    for (int it = 0; it < TILE / 256; ++it) {
        int e = e0 + it * 256 + t;
        int src = ei[e];
        int dst = ei[EE + e];
        int b = dst >> 8;
        int r = atomicAdd(&cnt[b], 1);
        int p = tstart[b] + r;
        sword[p] = src | ((dst & 255) << 17);
        sdst[p] = gshift[b] + p;        // == b*CAP + bucket_base + r
    }
    __syncthreads();
#pragma unroll
    for (int it = 0; it < TILE / 256; ++it) {
        int i = it * 256 + t;
        words[sdst[i]] = sword[i];
    }
}

// ---------------- within-bucket sort to exact CSR (one block per bucket) ----------------
__global__ __launch_bounds__(256) void k_csr(const int* __restrict__ words, const int* __restrict__ gcount,
                                             int* __restrict__ ssrc, int* __restrict__ offs,
                                             int* __restrict__ offe) {
    __shared__ int hist[BNODES];
    __shared__ int sc[BNODES];
    __shared__ int base[BNODES];
    int t = threadIdx.x;
    int b = blockIdx.x;
    hist[t] = 0;
    __syncthreads();
    int cnt = gcount[b];
    const int* wp = words + (size_t)b * CAP;
    for (int p = t; p < cnt; p += 256) atomicAdd(&hist[wp[p] >> 17], 1);
    __syncthreads();
    int val = hist[t];
    sc[t] = val;
    __syncthreads();
    for (int d = 1; d < 256; d <<= 1) {
        int v2 = (t >= d) ? sc[t - d] : 0;
        __syncthreads();
        sc[t] += v2;
        __syncthreads();
    }
    base[t] = sc[t] - val;              // exclusive scan
    int gbase = b * CAP;
    offs[b * BNODES + t] = gbase + base[t];
    offe[b * BNODES + t] = gbase + sc[t];
    __syncthreads();
    hist[t] = 0;                        // reuse as per-node cursor
    __syncthreads();
    for (int p = t; p < cnt; p += 256) {
        int w = wp[p];
        int dl = w >> 17;
        int r = atomicAdd(&hist[dl], 1);
        ssrc[gbase + base[dl] + r] = w & 0x1FFFF;
    }
}

// ---------------- fused prep: weight transposes + head fold + zero-init ----------------
__global__ __launch_bounds__(256) void k_prep(const float* __restrict__ mW1, const float* __restrict__ mW2,
                                              const float* __restrict__ mW3, const float* __restrict__ vW,
                                              const float* __restrict__ vb, const float* __restrict__ aW,
                                              const float* __restrict__ ab,
                                              _Float16* __restrict__ W1T, _Float16* __restrict__ W2T,
                                              _Float16* __restrict__ W3T, _Float16* __restrict__ BqT,
                                              float* __restrict__ biasq, int* __restrict__ gcount,
                                              float* __restrict__ bns) {
    int i = blockIdx.x * 256 + threadIdx.x;     // 262144 threads
    {
        int k = i >> 8, n = i & 255;
        W1T[(size_t)n * 1024 + k] = (_Float16)mW1[i];
    }
    if (i < 65536) {
        int k = i >> 8, n = i & 255;
        W2T[n * 256 + k] = (_Float16)mW2[i];
        W3T[n * 256 + k] = (_Float16)mW3[i];
    }
    if (i < 16384) {
        int f = i >> 6, j = i & 63;
        int n = j >> 1, a = j & 1;
        float wa = aW[n * 512 + f * 2 + a];
        float wo = aW[n * 512 + f * 2 + (1 - a)];
        BqT[j * 256 + f] = (_Float16)(vW[f] + 0.5f * (wa - wo));
    }
    if (i < 64) biasq[i] = vb[0] + 0.5f * (ab[i] - ab[i ^ 1]);
    if (i < 512) gcount[i] = 0;
    if (i < 192) bns[i] = 0.f;
}

// ---------------- layer-1 pre-transform (u = x@(Wt-Wb)+b1 fp32, v = x@Wb fp16) ------------
__global__ __launch_bounds__(256) void k_pre1(const float* __restrict__ x, const float* __restrict__ W1,
                                              const float* __restrict__ b1, float* __restrict__ u,
                                              __half* __restrict__ v) {
    int t = blockIdx.x * 256 + threadIdx.x;     // N*16 threads
    int n = t >> 4, c = t & 15;
    float x0 = x[n * 2], x1 = x[n * 2 + 1];
    float w0 = W1[c], w1 = W1[16 + c], w2 = W1[32 + c], w3 = W1[48 + c];
    u[t] = b1[c] + x0 * (w0 - w2) + x1 * (w1 - w3);
    v[t] = __float2half(x0 * w2 + x1 * w3);
    if (blockIdx.x == 0 && t < 16) v[NN * 16 + t] = __float2half(-60000.0f);
}

// ---------------- fused BN+ReLU + pre-transform for layers 2/3 ----------------
__global__ __launch_bounds__(256) void k_bnpre(const float* __restrict__ y, const float* __restrict__ bns,
                                               const float* __restrict__ g, const float* __restrict__ bb,
                                               const float* __restrict__ W1, const float* __restrict__ b1,
                                               float* __restrict__ u, __half* __restrict__ v) {
    __shared__ float sh[16][33];
    __shared__ float wd[32][16];
    __shared__ float wv[32][16];
    __shared__ float scL[32], soL[32];
    int t = threadIdx.x;
    if (t < 32) {
        const float inv_n = 1.0f / (float)NN;
        float mean = bns[t] * inv_n;
        float var = bns[32 + t] * inv_n - mean * mean;
        float s = g[t] * rsqrtf(var + EPS);
        scL[t] = s;
        soL[t] = bb[t] - mean * s;
    }
    for (int i = t; i < 512; i += 256) {
        int f = i >> 4, c = i & 15;
        float wt = W1[i];
        float wb = W1[512 + i];
        wd[f][c] = wt - wb;
        wv[f][c] = wb;
    }
    __syncthreads();
    int nb = blockIdx.x * 16;
    for (int i = t; i < 512; i += 256) {
        int col = i & 31;
        sh[i >> 5][col] = fmaxf(y[nb * 32 + i] * scL[col] + soL[col], 0.f);
    }
    __syncthreads();
    int c = t & 15, nl = t >> 4;
    float uu = b1[c], vv = 0.f;
#pragma unroll
    for (int f = 0; f < 32; ++f) {
        float hv = sh[nl][f];
        uu += hv * wd[f][c];
        vv += hv * wv[f][c];
    }
    int n = nb + nl;
    u[n * 16 + c] = uu;
    v[n * 16 + c] = __float2half(vv);
    if (blockIdx.x == 0 && t < 16) v[NN * 16 + t] = __float2half(-60000.0f);
}

// ---------------- CSR gather: 8 lanes/node, 16-wide MLP (avg degree in one burst) ----------
__global__ __launch_bounds__(256) void k_gather(const float* __restrict__ u, const __half* __restrict__ v,
                                                const int* __restrict__ ssrc, const int* __restrict__ offs,
                                                const int* __restrict__ offe,
                                                const float* __restrict__ W2, const float* __restrict__ b2,
                                                float* __restrict__ y) {
    __shared__ float sw2[512];          // [k][32]
    __shared__ float sagg[32 * 18];
    __shared__ float cntL[32];
    int t = threadIdx.x;
    float w2a = W2[t], w2b = W2[t + 256];         // stage in regs; LDS write after gather
    float b2r0 = b2[(t & 7) * 4], b2r1 = b2[(t & 7) * 4 + 1];
    float b2r2 = b2[(t & 7) * 4 + 2], b2r3 = b2[(t & 7) * 4 + 3];
    int nl = t >> 3, c2 = t & 7;
    int n = blockIdx.x * 32 + nl;
    int s0 = offs[n], e0 = offe[n];
    float2 uc = *(const float2*)(u + (size_t)n * 16 + 2 * c2);
    float a0 = 0.f, a1 = 0.f;
    for (int p = s0; p < e0; p += 16) {
        int idx[16];
#pragma unroll
        for (int i = 0; i < 16; ++i) idx[i] = (p + i < e0) ? ssrc[p + i] : NN;
        float2 vv[16];
#pragma unroll
        for (int i = 0; i < 16; ++i)
            vv[i] = __half22float2(*(const __half2*)(v + (size_t)idx[i] * 16 + 2 * c2));
#pragma unroll
        for (int i = 0; i < 16; ++i) {
            a0 += fmaxf(uc.x + vv[i].x, 0.f);
            a1 += fmaxf(uc.y + vv[i].y, 0.f);
        }
    }
    sagg[nl * 18 + 2 * c2] = a0;
    sagg[nl * 18 + 2 * c2 + 1] = a1;
    if (c2 == 0) cntL[nl] = (float)(e0 - s0);
    sw2[t] = w2a;
    sw2[t + 256] = w2b;
    __syncthreads();
    int node = t >> 3, oc = (t & 7) * 4;
    float cw = cntL[node];
    float o0 = b2r0 * cw, o1 = b2r1 * cw, o2 = b2r2 * cw, o3 = b2r3 * cw;
#pragma unroll
    for (int k = 0; k < 16; ++k) {
        float a = sagg[node * 18 + k];
        o0 += a * sw2[k * 32 + oc];
        o1 += a * sw2[k * 32 + oc + 1];
        o2 += a * sw2[k * 32 + oc + 2];
        o3 += a * sw2[k * 32 + oc + 3];
    }
    *(float4*)(y + (size_t)(blockIdx.x * 32 + node) * 32 + oc) = make_float4(o0, o1, o2, o3);
}

// ---------------- BN stats straight from y: 256 blocks x 512 rows ----------------
__global__ __launch_bounds__(256) void k_bnstat2(const float* __restrict__ y, float* __restrict__ bns) {
    __shared__ float ssm[8][33];
    __shared__ float ssq[8][33];
    int t = threadIdx.x;
    int c = t & 31, g = t >> 5;
    size_t r0 = (size_t)blockIdx.x * 512;
    float sm = 0.f, sq = 0.f;
    for (int i = 0; i < 64; ++i) {
        float val = y[(r0 + g + (size_t)i * 8) * 32 + c];
        sm += val;
        sq += val * val;
    }
    ssm[g][c] = sm;
    ssq[g][c] = sq;
    __syncthreads();
    if (t < 32) {
        float a = 0.f, bq = 0.f;
#pragma unroll
        for (int gg = 0; gg < 8; ++gg) { a += ssm[gg][t]; bq += ssq[gg][t]; }
        atomicAdd(&bns[t], a);
        atomicAdd(&bns[32 + t], bq);
    }
}

// ---------------- layer-3 BN+ReLU -> fp16 GEMM input only ----------------
__global__ __launch_bounds__(256) void k_bnrelu16(const float* __restrict__ y, const float* __restrict__ bns,
                                                  const float* __restrict__ g, const float* __restrict__ bb,
                                                  _Float16* __restrict__ h16) {
    int t = blockIdx.x * 256 + threadIdx.x;
    int j = t & 31;
    const float inv_n = 1.0f / (float)NN;
    float mean = bns[j] * inv_n;
    float var = bns[32 + j] * inv_n - mean * mean;
    float sc = g[j] * rsqrtf(var + EPS);
    float sh = bb[j] - mean * sc;
    h16[t] = (_Float16)fmaxf(y[t] * sc + sh, 0.f);
}

// ---------------- MFMA fp16 GEMM: C = [relu](A[M,K] @ BT[N,K]^T + bias) ----------------
__global__ __launch_bounds__(256) void k_mgemm(const _Float16* __restrict__ A, const _Float16* __restrict__ BT,
                                               const float* __restrict__ bias, float* __restrict__ Cf,
                                               _Float16* __restrict__ Ch, int M, int N, int K,
                                               int relu, int out16) {
    int tid = threadIdx.x;
    int w = tid >> 6, l = tid & 63, q = l >> 4, r = l & 15;
    int rowBase = blockIdx.x * 64;
    int col = blockIdx.y * 64 + w * 16 + r;
    const _Float16* ap = A + (size_t)(rowBase + r) * K + q * 8;
    const _Float16* bp = BT + (size_t)col * K + q * 8;
    f32x4 z = {0.f, 0.f, 0.f, 0.f};
    f32x4 acc[4] = {z, z, z, z};
    for (int k0 = 0; k0 < K; k0 += 32) {
        f16x8 bf = *(const f16x8*)(bp + k0);
        f16x8 a0 = *(const f16x8*)(ap + k0);
        f16x8 a1 = *(const f16x8*)(ap + k0 + (size_t)16 * K);
        f16x8 a2 = *(const f16x8*)(ap + k0 + (size_t)32 * K);
        f16x8 a3 = *(const f16x8*)(ap + k0 + (size_t)48 * K);
        acc[0] = __builtin_amdgcn_mfma_f32_16x16x32_f16(a0, bf, acc[0], 0, 0, 0);
        acc[1] = __builtin_amdgcn_mfma_f32_16x16x32_f16(a1, bf, acc[1], 0, 0, 0);
        acc[2] = __builtin_amdgcn_mfma_f32_16x16x32_f16(a2, bf, acc[2], 0, 0, 0);
        acc[3] = __builtin_amdgcn_mfma_f32_16x16x32_f16(a3, bf, acc[3], 0, 0, 0);
    }
    float bv = bias[col];
#pragma unroll
    for (int rt = 0; rt < 4; ++rt) {
#pragma unroll
        for (int i = 0; i < 4; ++i) {
            int row = rowBase + rt * 16 + q * 4 + i;
            float val = acc[rt][i] + bv;
            if (relu) val = fmaxf(val, 0.f);
            if (out16) Ch[(size_t)row * N + col] = (_Float16)val;
            else       Cf[(size_t)row * N + col] = val;
        }
    }
}

extern "C" void kernel_launch(void* const* d_in, const int* in_sizes, int n_in,
                              void* d_out, int out_size, void* d_ws, size_t ws_size,
                              hipStream_t stream) {
    const float* x    = (const float*)d_in[0];
    const int*   ei   = (const int*)d_in[1];
    const float* c1W1 = (const float*)d_in[2];
    const float* c1b1 = (const float*)d_in[3];
    const float* c1W2 = (const float*)d_in[4];
    const float* c1b2 = (const float*)d_in[5];
    const float* c2W1 = (const float*)d_in[6];
    const float* c2b1 = (const float*)d_in[7];
    const float* c2W2 = (const float*)d_in[8];
    const float* c2b2 = (const float*)d_in[9];
    const float* c3W1 = (const float*)d_in[10];
    const float* c3b1 = (const float*)d_in[11];
    const float* c3W2 = (const float*)d_in[12];
    const float* c3b2 = (const float*)d_in[13];
    const float* bn_g = (const float*)d_in[14];
    const float* bn_b = (const float*)d_in[15];
    const float* mW1  = (const float*)d_in[16];
    const float* mb1  = (const float*)d_in[17];
    const float* mW2  = (const float*)d_in[18];
    const float* mb2  = (const float*)d_in[19];
    const float* mW3  = (const float*)d_in[20];
    const float* mb3  = (const float*)d_in[21];
    const float* vW   = (const float*)d_in[22];
    const float* vb   = (const float*)d_in[23];
    const float* aW   = (const float*)d_in[24];
    const float* ab   = (const float*)d_in[25];
    float* out = (float*)d_out;

    char* p = (char*)d_ws;
    auto take = [&](size_t bytes) {
        char* r = p;
        p += (bytes + 255) & ~(size_t)255;
        return r;
    };
    int*       gcount = (int*)take((size_t)BKT * 4);
    int*       words  = (int*)take((size_t)BKT * CAP * 4);
    int*       ssrc   = (int*)take((size_t)BKT * CAP * 4);
    int*       offs   = (int*)take((size_t)NN * 4);
    int*       offe   = (int*)take((size_t)NN * 4);
    float*     u      = (float*)take((size_t)NN * HH * 4);
    __half*    v      = (__half*)take((size_t)(NN + 1) * HH * 2);
    float*     y      = (float*)take((size_t)NN * SS * 4);
    _Float16*  h16    = (_Float16*)take((size_t)NN * SS * 2);
    float*     bns    = (float*)take(3 * 64 * 4);
    _Float16*  W1T    = (_Float16*)take((size_t)256 * 1024 * 2);
    _Float16*  W2T    = (_Float16*)take((size_t)256 * 256 * 2);
    _Float16*  W3T    = (_Float16*)take((size_t)256 * 256 * 2);
    _Float16*  BqT    = (_Float16*)take((size_t)64 * 256 * 2);
    float*     biasq  = (float*)take(64 * 4);
    _Float16*  Xa     = (_Float16*)take((size_t)BB * 256 * 2);
    _Float16*  Xb     = (_Float16*)take((size_t)BB * 256 * 2);

    // fused prep (weights transpose + head fold + gcount/bns zero-init)
    k_prep<<<1024, 256, 0, stream>>>(mW1, mW2, mW3, vW, vb, aW, ab,
                                     W1T, W2T, W3T, BqT, biasq, gcount, bns);

    // CSR build: LDS-staged bucket partition, then within-bucket sort
    k_bsort<<<EE / TILE, 256, 0, stream>>>(ei, gcount, words);
    k_csr<<<BKT, 256, 0, stream>>>(words, gcount, ssrc, offs, offe);

    // layer 1
    k_pre1<<<NN * 16 / 256, 256, 0, stream>>>(x, c1W1, c1b1, u, v);
    k_gather<<<NN / 32, 256, 0, stream>>>(u, v, ssrc, offs, offe, c1W2, c1b2, y);
    k_bnstat2<<<256, 256, 0, stream>>>(y, bns);
    // layer 2 (fused BN+ReLU+pre)
    k_bnpre<<<NN / 16, 256, 0, stream>>>(y, bns, bn_g, bn_b, c2W1, c2b1, u, v);
    k_gather<<<NN / 32, 256, 0, stream>>>(u, v, ssrc, offs, offe, c2W2, c2b2, y);
    k_bnstat2<<<256, 256, 0, stream>>>(y, bns + 64);
    // layer 3 (fused BN+ReLU+pre)
    k_bnpre<<<NN / 16, 256, 0, stream>>>(y, bns + 64, bn_g + 32, bn_b + 32, c3W1, c3b1, u, v);
    k_gather<<<NN / 32, 256, 0, stream>>>(u, v, ssrc, offs, offe, c3W2, c3b2, y);
    k_bnstat2<<<256, 256, 0, stream>>>(y, bns + 128);
    k_bnrelu16<<<NN * 32 / 256, 256, 0, stream>>>(y, bns + 128, bn_g + 64, bn_b + 64, h16);

    // dense head MLP on matrix cores (fp16 in, fp32 accumulate)
    k_mgemm<<<dim3(BB / 64, 4), 256, 0, stream>>>(h16, W1T, mb1, nullptr, Xa, BB, 256, 1024, 1, 1);
    k_mgemm<<<dim3(BB / 64, 4), 256, 0, stream>>>(Xa, W2T, mb2, nullptr, Xb, BB, 256, 256, 1, 1);
    k_mgemm<<<dim3(BB / 64, 4), 256, 0, stream>>>(Xb, W3T, mb3, nullptr, Xa, BB, 256, 256, 1, 1);
    // dueling heads folded into one GEMM: out = X @ BqT^T + biasq
    k_mgemm<<<dim3(BB / 64, 1), 256, 0, stream>>>(Xa, BqT, biasq, out, nullptr, BB, 64, 256, 0, 0);
}

// Round 13
// 333.529 us; speedup vs baseline: 3.0359x; 1.1063x over previous
//
#include <hip/hip_runtime.h>
#include <hip/hip_fp16.h>

#define NN 131072        // nodes
#define EE 2097152       // edges
#define SS 32            // channels
#define HH 16            // hidden
#define BB 4096          // graphs
#define EPS 1e-5f

#define BKT 512          // buckets (dst >> 8)
#define BNODES 256       // nodes per bucket
#define CAP 4864         // bucket capacity in words (avg 4096, +12 sigma)
#define SCAP 8192        // bucket capacity in ssrc (padded-to-16 per node)
#define TILE 8192        // edges per bsort block

typedef _Float16 f16x8 __attribute__((ext_vector_type(8)));
typedef float f32x4 __attribute__((ext_vector_type(4)));

// ---------------- bucket partition, LDS-staged, 1024 threads (16 waves/CU) ----------------
// R12 theory: 256x256 = 4 waves/CU couldn't hide LDS-atomic/copy latency.
__global__ __launch_bounds__(1024) void k_bsort(const int* __restrict__ ei, int* __restrict__ gcount,
                                                int* __restrict__ words) {
    __shared__ int cnt[BKT];
    __shared__ int tstart[BKT];
    __shared__ int gshift[BKT];
    __shared__ int sc[BKT];
    __shared__ int sword[TILE];
    __shared__ int sdst[TILE];
    int t = threadIdx.x;
    if (t < BKT) cnt[t] = 0;
    __syncthreads();
    int e0 = blockIdx.x * TILE;
#pragma unroll
    for (int it = 0; it < TILE / 1024; ++it) {
        int dst = ei[EE + e0 + it * 1024 + t];
        atomicAdd(&cnt[dst >> 8], 1);
    }
    __syncthreads();
    int val = (t < BKT) ? cnt[t] : 0;
    if (t < BKT) sc[t] = val;
    __syncthreads();
    for (int d = 1; d < BKT; d <<= 1) {
        int v2 = (t >= d && t < BKT) ? sc[t - d] : 0;
        __syncthreads();
        if (t < BKT) sc[t] += v2;
        __syncthreads();
    }
    if (t < BKT) {
        int excl = sc[t] - val;
        tstart[t] = excl;
        gshift[t] = t * CAP + atomicAdd(&gcount[t], val) - excl;   // includes segment base
        cnt[t] = 0;                     // reuse as intra-tile cursor
    }
    __syncthreads();
#pragma unroll
    for (int it = 0; it < TILE / 1024; ++it) {
        int e = e0 + it * 1024 + t;
        int src = ei[e];
        int dst = ei[EE + e];
        int b = dst >> 8;
        int r = atomicAdd(&cnt[b], 1);
        int p = tstart[b] + r;
        sword[p] = src | ((dst & 255) << 17);
        sdst[p] = gshift[b] + p;        // == b*CAP + bucket_base + rank
    }
    __syncthreads();
#pragma unroll
    for (int it = 0; it < TILE / 1024; ++it) {
        int i = it * 1024 + t;
        words[sdst[i]] = sword[i];      // position-ordered: full-line bursts
    }
}

// ---------------- within-bucket sort to CSR with 16-padded node segments ----------------
// Pad slots hold NN (dummy v row -> relu contributes 0), so k_gather's loop is branchless.
__global__ __launch_bounds__(512) void k_csr(const int* __restrict__ words, const int* __restrict__ gcount,
                                             int* __restrict__ ssrc, int* __restrict__ offs,
                                             int* __restrict__ offe) {
    __shared__ int hist[BNODES];
    __shared__ int sc[BNODES];
    __shared__ int base[BNODES];
    int t = threadIdx.x;
    int b = blockIdx.x;
    if (t < BNODES) hist[t] = 0;
    __syncthreads();
    int cnt = gcount[b];
    const int* wp = words + (size_t)b * CAP;
    for (int p = t; p < cnt; p += 512) atomicAdd(&hist[wp[p] >> 17], 1);
    __syncthreads();
    int val = 0, pval = 0;
    if (t < BNODES) {
        val = hist[t];
        pval = (val + 15) & ~15;        // padded length
        sc[t] = pval;
    }
    __syncthreads();
    for (int d = 1; d < BNODES; d <<= 1) {
        int v2 = (t >= d && t < BNODES) ? sc[t - d] : 0;
        __syncthreads();
        if (t < BNODES) sc[t] += v2;
        __syncthreads();
    }
    int gbase = b * SCAP;
    if (t < BNODES) {
        base[t] = sc[t] - pval;         // exclusive scan of padded lengths
        offs[b * BNODES + t] = gbase + base[t];
        offe[b * BNODES + t] = gbase + base[t] + val;
        hist[t] = 0;                    // reuse as per-node cursor
    }
    __syncthreads();
    for (int p = t; p < cnt; p += 512) {
        int w = wp[p];
        int dl = w >> 17;
        int r = atomicAdd(&hist[dl], 1);
        ssrc[gbase + base[dl] + r] = w & 0x1FFFF;
    }
    if (t < BNODES) {                   // pad fill: disjoint range [val, pval), no barrier needed
        int s = gbase + base[t];
        for (int i = val; i < pval; ++i) ssrc[s + i] = NN;
    }
}

// ---------------- fused prep: weight transposes + head fold + zero-init ----------------
__global__ __launch_bounds__(256) void k_prep(const float* __restrict__ mW1, const float* __restrict__ mW2,
                                              const float* __restrict__ mW3, const float* __restrict__ vW,
                                              const float* __restrict__ vb, const float* __restrict__ aW,
                                              const float* __restrict__ ab,
                                              _Float16* __restrict__ W1T, _Float16* __restrict__ W2T,
                                              _Float16* __restrict__ W3T, _Float16* __restrict__ BqT,
                                              float* __restrict__ biasq, int* __restrict__ gcount,
                                              float* __restrict__ bns) {
    int i = blockIdx.x * 256 + threadIdx.x;     // 262144 threads
    {
        int k = i >> 8, n = i & 255;
        W1T[(size_t)n * 1024 + k] = (_Float16)mW1[i];
    }
    if (i < 65536) {
        int k = i >> 8, n = i & 255;
        W2T[n * 256 + k] = (_Float16)mW2[i];
        W3T[n * 256 + k] = (_Float16)mW3[i];
    }
    if (i < 16384) {
        int f = i >> 6, j = i & 63;
        int n = j >> 1, a = j & 1;
        float wa = aW[n * 512 + f * 2 + a];
        float wo = aW[n * 512 + f * 2 + (1 - a)];
        BqT[j * 256 + f] = (_Float16)(vW[f] + 0.5f * (wa - wo));
    }
    if (i < 64) biasq[i] = vb[0] + 0.5f * (ab[i] - ab[i ^ 1]);
    if (i < 512) gcount[i] = 0;
    if (i < 192) bns[i] = 0.f;
}

// ---------------- layer-1 pre-transform (u = x@(Wt-Wb)+b1 fp32, v = x@Wb fp16) ------------
__global__ __launch_bounds__(256) void k_pre1(const float* __restrict__ x, const float* __restrict__ W1,
                                              const float* __restrict__ b1, float* __restrict__ u,
                                              __half* __restrict__ v) {
    int t = blockIdx.x * 256 + threadIdx.x;     // N*16 threads
    int n = t >> 4, c = t & 15;
    float x0 = x[n * 2], x1 = x[n * 2 + 1];
    float w0 = W1[c], w1 = W1[16 + c], w2 = W1[32 + c], w3 = W1[48 + c];
    u[t] = b1[c] + x0 * (w0 - w2) + x1 * (w1 - w3);
    v[t] = __float2half(x0 * w2 + x1 * w3);
    if (blockIdx.x == 0 && t < 16) v[NN * 16 + t] = __float2half(-60000.0f);
}

// ---------------- fused BN+ReLU + pre-transform for layers 2/3 ----------------
__global__ __launch_bounds__(256) void k_bnpre(const float* __restrict__ y, const float* __restrict__ bns,
                                               const float* __restrict__ g, const float* __restrict__ bb,
                                               const float* __restrict__ W1, const float* __restrict__ b1,
                                               float* __restrict__ u, __half* __restrict__ v) {
    __shared__ float sh[16][33];
    __shared__ float wd[32][16];
    __shared__ float wv[32][16];
    __shared__ float scL[32], soL[32];
    int t = threadIdx.x;
    if (t < 32) {
        const float inv_n = 1.0f / (float)NN;
        float mean = bns[t] * inv_n;
        float var = bns[32 + t] * inv_n - mean * mean;
        float s = g[t] * rsqrtf(var + EPS);
        scL[t] = s;
        soL[t] = bb[t] - mean * s;
    }
    for (int i = t; i < 512; i += 256) {
        int f = i >> 4, c = i & 15;
        float wt = W1[i];
        float wb = W1[512 + i];
        wd[f][c] = wt - wb;
        wv[f][c] = wb;
    }
    __syncthreads();
    int nb = blockIdx.x * 16;
    for (int i = t; i < 512; i += 256) {
        int col = i & 31;
        sh[i >> 5][col] = fmaxf(y[nb * 32 + i] * scL[col] + soL[col], 0.f);
    }
    __syncthreads();
    int c = t & 15, nl = t >> 4;
    float uu = b1[c], vv = 0.f;
#pragma unroll
    for (int f = 0; f < 32; ++f) {
        float hv = sh[nl][f];
        uu += hv * wd[f][c];
        vv += hv * wv[f][c];
    }
    int n = nb + nl;
    u[n * 16 + c] = uu;
    v[n * 16 + c] = __float2half(vv);
    if (blockIdx.x == 0 && t < 16) v[NN * 16 + t] = __float2half(-60000.0f);
}

// ---------------- CSR gather: branchless 16-wide loop over padded segments ----------------
__global__ __launch_bounds__(256) void k_gather(const float* __restrict__ u, const __half* __restrict__ v,
                                                const int* __restrict__ ssrc, const int* __restrict__ offs,
                                                const int* __restrict__ offe,
                                                const float* __restrict__ W2, const float* __restrict__ b2,
                                                float* __restrict__ y) {
    __shared__ float sw2[512];          // [k][32]
    __shared__ float sagg[32 * 18];
    __shared__ float cntL[32];
    int t = threadIdx.x;
    float w2a = W2[t], w2b = W2[t + 256];         // stage in regs; LDS write after gather
    float b2r0 = b2[(t & 7) * 4], b2r1 = b2[(t & 7) * 4 + 1];
    float b2r2 = b2[(t & 7) * 4 + 2], b2r3 = b2[(t & 7) * 4 + 3];
    int nl = t >> 3, c2 = t & 7;
    int n = blockIdx.x * 32 + nl;
    int s0 = offs[n], e0 = offe[n];
    int pe = s0 + ((e0 - s0 + 15) & ~15);         // padded end (pad slots -> node NN -> 0)
    float2 uc = *(const float2*)(u + (size_t)n * 16 + 2 * c2);
    float a0 = 0.f, a1 = 0.f;
    for (int p = s0; p < pe; p += 16) {
        int idx[16];
#pragma unroll
        for (int i = 0; i < 16; ++i) idx[i] = ssrc[p + i];
        float2 vv[16];
#pragma unroll
        for (int i = 0; i < 16; ++i)
            vv[i] = __half22float2(*(const __half2*)(v + (size_t)idx[i] * 16 + 2 * c2));
#pragma unroll
        for (int i = 0; i < 16; ++i) {
            a0 += fmaxf(uc.x + vv[i].x, 0.f);
            a1 += fmaxf(uc.y + vv[i].y, 0.f);
        }
    }
    sagg[nl * 18 + 2 * c2] = a0;
    sagg[nl * 18 + 2 * c2 + 1] = a1;
    if (c2 == 0) cntL[nl] = (float)(e0 - s0);
    sw2[t] = w2a;
    sw2[t + 256] = w2b;
    __syncthreads();
    int node = t >> 3, oc = (t & 7) * 4;
    float cw = cntL[node];
    float o0 = b2r0 * cw, o1 = b2r1 * cw, o2 = b2r2 * cw, o3 = b2r3 * cw;
#pragma unroll
    for (int k = 0; k < 16; ++k) {
        float a = sagg[node * 18 + k];
        o0 += a * sw2[k * 32 + oc];
        o1 += a * sw2[k * 32 + oc + 1];
        o2 += a * sw2[k * 32 + oc + 2];
        o3 += a * sw2[k * 32 + oc + 3];
    }
    *(float4*)(y + (size_t)(blockIdx.x * 32 + node) * 32 + oc) = make_float4(o0, o1, o2, o3);
}

// ---------------- BN stats straight from y: 256 blocks x 512 rows ----------------
__global__ __launch_bounds__(256) void k_bnstat2(const float* __restrict__ y, float* __restrict__ bns) {
    __shared__ float ssm[8][33];
    __shared__ float ssq[8][33];
    int t = threadIdx.x;
    int c = t & 31, g = t >> 5;
    size_t r0 = (size_t)blockIdx.x * 512;
    float sm = 0.f, sq = 0.f;
    for (int i = 0; i < 64; ++i) {
        float val = y[(r0 + g + (size_t)i * 8) * 32 + c];
        sm += val;
        sq += val * val;
    }
    ssm[g][c] = sm;
    ssq[g][c] = sq;
    __syncthreads();
    if (t < 32) {
        float a = 0.f, bq = 0.f;
#pragma unroll
        for (int gg = 0; gg < 8; ++gg) { a += ssm[gg][t]; bq += ssq[gg][t]; }
        atomicAdd(&bns[t], a);
        atomicAdd(&bns[32 + t], bq);
    }
}

// ---------------- layer-3 BN+ReLU -> fp16 GEMM input only ----------------
__global__ __launch_bounds__(256) void k_bnrelu16(const float* __restrict__ y, const float* __restrict__ bns,
                                                  const float* __restrict__ g, const float* __restrict__ bb,
                                                  _Float16* __restrict__ h16) {
    int t = blockIdx.x * 256 + threadIdx.x;
    int j = t & 31;
    const float inv_n = 1.0f / (float)NN;
    float mean = bns[j] * inv_n;
    float var = bns[32 + j] * inv_n - mean * mean;
    float sc = g[j] * rsqrtf(var + EPS);
    float sh = bb[j] - mean * sc;
    h16[t] = (_Float16)fmaxf(y[t] * sc + sh, 0.f);
}

// ---------------- MFMA fp16 GEMM: C = [relu](A[M,K] @ BT[N,K]^T + bias) ----------------
__global__ __launch_bounds__(256) void k_mgemm(const _Float16* __restrict__ A, const _Float16* __restrict__ BT,
                                               const float* __restrict__ bias, float* __restrict__ Cf,
                                               _Float16* __restrict__ Ch, int M, int N, int K,
                                               int relu, int out16) {
    int tid = threadIdx.x;
    int w = tid >> 6, l = tid & 63, q = l >> 4, r = l & 15;
    int rowBase = blockIdx.x * 64;
    int col = blockIdx.y * 64 + w * 16 + r;
    const _Float16* ap = A + (size_t)(rowBase + r) * K + q * 8;
    const _Float16* bp = BT + (size_t)col * K + q * 8;
    f32x4 z = {0.f, 0.f, 0.f, 0.f};
    f32x4 acc[4] = {z, z, z, z};
    for (int k0 = 0; k0 < K; k0 += 32) {
        f16x8 bf = *(const f16x8*)(bp + k0);
        f16x8 a0 = *(const f16x8*)(ap + k0);
        f16x8 a1 = *(const f16x8*)(ap + k0 + (size_t)16 * K);
        f16x8 a2 = *(const f16x8*)(ap + k0 + (size_t)32 * K);
        f16x8 a3 = *(const f16x8*)(ap + k0 + (size_t)48 * K);
        acc[0] = __builtin_amdgcn_mfma_f32_16x16x32_f16(a0, bf, acc[0], 0, 0, 0);
        acc[1] = __builtin_amdgcn_mfma_f32_16x16x32_f16(a1, bf, acc[1], 0, 0, 0);
        acc[2] = __builtin_amdgcn_mfma_f32_16x16x32_f16(a2, bf, acc[2], 0, 0, 0);
        acc[3] = __builtin_amdgcn_mfma_f32_16x16x32_f16(a3, bf, acc[3], 0, 0, 0);
    }
    float bv = bias[col];
#pragma unroll
    for (int rt = 0; rt < 4; ++rt) {
#pragma unroll
        for (int i = 0; i < 4; ++i) {
            int row = rowBase + rt * 16 + q * 4 + i;
            float val = acc[rt][i] + bv;
            if (relu) val = fmaxf(val, 0.f);
            if (out16) Ch[(size_t)row * N + col] = (_Float16)val;
            else       Cf[(size_t)row * N + col] = val;
        }
    }
}

extern "C" void kernel_launch(void* const* d_in, const int* in_sizes, int n_in,
                              void* d_out, int out_size, void* d_ws, size_t ws_size,
                              hipStream_t stream) {
    const float* x    = (const float*)d_in[0];
    const int*   ei   = (const int*)d_in[1];
    const float* c1W1 = (const float*)d_in[2];
    const float* c1b1 = (const float*)d_in[3];
    const float* c1W2 = (const float*)d_in[4];
    const float* c1b2 = (const float*)d_in[5];
    const float* c2W1 = (const float*)d_in[6];
    const float* c2b1 = (const float*)d_in[7];
    const float* c2W2 = (const float*)d_in[8];
    const float* c2b2 = (const float*)d_in[9];
    const float* c3W1 = (const float*)d_in[10];
    const float* c3b1 = (const float*)d_in[11];
    const float* c3W2 = (const float*)d_in[12];
    const float* c3b2 = (const float*)d_in[13];
    const float* bn_g = (const float*)d_in[14];
    const float* bn_b = (const float*)d_in[15];
    const float* mW1  = (const float*)d_in[16];
    const float* mb1  = (const float*)d_in[17];
    const float* mW2  = (const float*)d_in[18];
    const float* mb2  = (const float*)d_in[19];
    const float* mW3  = (const float*)d_in[20];
    const float* mb3  = (const float*)d_in[21];
    const float* vW   = (const float*)d_in[22];
    const float* vb   = (const float*)d_in[23];
    const float* aW   = (const float*)d_in[24];
    const float* ab   = (const float*)d_in[25];
    float* out = (float*)d_out;

    char* p = (char*)d_ws;
    auto take = [&](size_t bytes) {
        char* r = p;
        p += (bytes + 255) & ~(size_t)255;
        return r;
    };
    int*       gcount = (int*)take((size_t)BKT * 4);
    int*       words  = (int*)take((size_t)BKT * CAP * 4);       // ~10 MB bucketed edges
    int*       ssrc   = (int*)take((size_t)BKT * SCAP * 4);      // 16 MB padded CSR srcs
    int*       offs   = (int*)take((size_t)NN * 4);
    int*       offe   = (int*)take((size_t)NN * 4);
    float*     u      = (float*)take((size_t)NN * HH * 4);
    __half*    v      = (__half*)take((size_t)(NN + 1) * HH * 2);
    float*     y      = (float*)take((size_t)NN * SS * 4);
    _Float16*  h16    = (_Float16*)take((size_t)NN * SS * 2);
    float*     bns    = (float*)take(3 * 64 * 4);
    _Float16*  W1T    = (_Float16*)take((size_t)256 * 1024 * 2);
    _Float16*  W2T    = (_Float16*)take((size_t)256 * 256 * 2);
    _Float16*  W3T    = (_Float16*)take((size_t)256 * 256 * 2);
    _Float16*  BqT    = (_Float16*)take((size_t)64 * 256 * 2);
    float*     biasq  = (float*)take(64 * 4);
    _Float16*  Xa     = (_Float16*)take((size_t)BB * 256 * 2);
    _Float16*  Xb     = (_Float16*)take((size_t)BB * 256 * 2);

    // fused prep (weights transpose + head fold + gcount/bns zero-init)
    k_prep<<<1024, 256, 0, stream>>>(mW1, mW2, mW3, vW, vb, aW, ab,
                                     W1T, W2T, W3T, BqT, biasq, gcount, bns);

    // CSR build: LDS-staged bucket partition (1024 thr), then padded within-bucket sort
    k_bsort<<<EE / TILE, 1024, 0, stream>>>(ei, gcount, words);
    k_csr<<<BKT, 512, 0, stream>>>(words, gcount, ssrc, offs, offe);

    // layer 1
    k_pre1<<<NN * 16 / 256, 256, 0, stream>>>(x, c1W1, c1b1, u, v);
    k_gather<<<NN / 32, 256, 0, stream>>>(u, v, ssrc, offs, offe, c1W2, c1b2, y);
    k_bnstat2<<<256, 256, 0, stream>>>(y, bns);
    // layer 2 (fused BN+ReLU+pre)
    k_bnpre<<<NN / 16, 256, 0, stream>>>(y, bns, bn_g, bn_b, c2W1, c2b1, u, v);
    k_gather<<<NN / 32, 256, 0, stream>>>(u, v, ssrc, offs, offe, c2W2, c2b2, y);
    k_bnstat2<<<256, 256, 0, stream>>>(y, bns + 64);
    // layer 3 (fused BN+ReLU+pre)
    k_bnpre<<<NN / 16, 256, 0, stream>>>(y, bns + 64, bn_g + 32, bn_b + 32, c3W1, c3b1, u, v);
    k_gather<<<NN / 32, 256, 0, stream>>>(u, v, ssrc, offs, offe, c3W2, c3b2, y);
    k_bnstat2<<<256, 256, 0, stream>>>(y, bns + 128);
    k_bnrelu16<<<NN * 32 / 256, 256, 0, stream>>>(y, bns + 128, bn_g + 64, bn_b + 64, h16);

    // dense head MLP on matrix cores (fp16 in, fp32 accumulate)
    k_mgemm<<<dim3(BB / 64, 4), 256, 0, stream>>>(h16, W1T, mb1, nullptr, Xa, BB, 256, 1024, 1, 1);
    k_mgemm<<<dim3(BB / 64, 4), 256, 0, stream>>>(Xa, W2T, mb2, nullptr, Xb, BB, 256, 256, 1, 1);
    k_mgemm<<<dim3(BB / 64, 4), 256, 0, stream>>>(Xb, W3T, mb3, nullptr, Xa, BB, 256, 256, 1, 1);
    // dueling heads folded into one GEMM: out = X @ BqT^T + biasq
    k_mgemm<<<dim3(BB / 64, 1), 256, 0, stream>>>(Xa, BqT, biasq, out, nullptr, BB, 64, 256, 0, 0);
}